// Round 13
// baseline (2035.321 us; speedup 1.0000x reference)
//
#include <hip/hip_runtime.h>
#include <math.h>

#define Bn 1024
#define Dn 512
#define Hn 512
#define Vn 8192
#define Tn 20
#define G4 2048

typedef _Float16 half8 __attribute__((ext_vector_type(8)));
typedef float f32x4 __attribute__((ext_vector_type(4)));

#define SCHEDB() __builtin_amdgcn_sched_barrier(0)
#define SBAR()   __builtin_amdgcn_s_barrier()

// ---------------- threefry2x32 (JAX-exact, 20 rounds) ----------------
__host__ __device__ __forceinline__ void threefry2x32(
    unsigned k0, unsigned k1, unsigned x0, unsigned x1,
    unsigned& y0, unsigned& y1) {
  unsigned ks2 = k0 ^ k1 ^ 0x1BD11BDAu;
#define TF_RND(r) { x0 += x1; x1 = (x1 << (r)) | (x1 >> (32 - (r))); x1 ^= x0; }
  x0 += k0; x1 += k1;
  TF_RND(13) TF_RND(15) TF_RND(26) TF_RND(6)
  x0 += k1; x1 += ks2 + 1u;
  TF_RND(17) TF_RND(29) TF_RND(16) TF_RND(24)
  x0 += ks2; x1 += k0 + 2u;
  TF_RND(13) TF_RND(15) TF_RND(26) TF_RND(6)
  x0 += k0; x1 += k1 + 3u;
  TF_RND(17) TF_RND(29) TF_RND(16) TF_RND(24)
  x0 += k1; x1 += ks2 + 4u;
  TF_RND(13) TF_RND(15) TF_RND(26) TF_RND(6)
  x0 += ks2; x1 += k0 + 5u;
#undef TF_RND
  y0 = x0; y1 = x1;
}

// f32 -> f16 hi/lo split. lo scaled by 2^11 to stay in f16 normal range.
__device__ __forceinline__ void split16(float v, _Float16& hi, _Float16& lo) {
  float h = (fabsf(v) < 6.2e-5f) ? 0.f : (float)(_Float16)v;  // keep hi out of f16-denorm
  hi = (_Float16)h;
  lo = (_Float16)((v - h) * 2048.0f);
}

// async 16B global->LDS. HW dest = wave-uniform base + lane*16; our per-lane
// addressing (row=f(lane>>2), chunk=lane&3) equals exactly that mapping.
__device__ __forceinline__ void gload16(void* l, const void* g) {
  __builtin_amdgcn_global_load_lds(
      (const __attribute__((address_space(1))) unsigned int*)g,
      (__attribute__((address_space(3))) unsigned int*)l, 16, 0, 0);
}

// ---------------- prep kernels (run every call; idempotent) ----------------
__global__ void k_prep(const float* __restrict__ w, _Float16* __restrict__ hi,
                       _Float16* __restrict__ lo, int n) {
  int i = blockIdx.x * blockDim.x + threadIdx.x;
  if (i >= n) return;
  split16(w[i], hi[i], lo[i]);
}

// gate-interleaved permutation: dst row u*4+g  <-  src row g*512+u
__global__ void k_prep_perm(const float* __restrict__ w, _Float16* __restrict__ hi,
                            _Float16* __restrict__ lo) {
  int i = blockIdx.x * blockDim.x + threadIdx.x;  // G4*Hn
  int rp = i >> 9, k = i & 511;
  int u = rp >> 2, g = rp & 3;
  split16(w[(size_t)((g << 9) + u) * 512 + k], hi[i], lo[i]);
}

__global__ void k_prep_bias(const float* __restrict__ bih, const float* __restrict__ bhh,
                            float* __restrict__ bp) {
  int i = blockIdx.x * blockDim.x + threadIdx.x;  // G4
  if (i >= G4) return;
  int u = i >> 2, g = i & 3;
  bp[i] = bih[(g << 9) + u] + bhh[(g << 9) + u];
}

__global__ void k_mask(float* __restrict__ mask) {
  int i = blockIdx.x * blockDim.x + threadIdx.x;
  if (i < Bn) mask[i] = 1.f;
}

// ================== LSTM cell epilogue (shared) ==================
__device__ __forceinline__ void cell_update(
    float (*gtile)[68], int tid, int bm, int u0, float* __restrict__ c,
    _Float16* __restrict__ hoh, _Float16* __restrict__ hol) {
#pragma unroll
  for (int j = 0; j < 8; ++j) {
    int idx = tid + (j << 8);
    int row = idx >> 4, ul = idx & 15;
    float4 gt = *(const float4*)&gtile[row][ul << 2];  // i,f,g,o
    size_t cidx = (size_t)(bm + row) * Hn + u0 + ul;
    float si = 1.0f / (1.0f + expf(-gt.x));
    float sf = 1.0f / (1.0f + expf(-gt.y));
    float tg = tanhf(gt.z);
    float so = 1.0f / (1.0f + expf(-gt.w));
    float cn = sf * c[cidx] + si * tg;
    c[cidx] = cn;
    float hv = so * tanhf(cn);
    split16(hv, hoh[cidx], hol[cidx]);
  }
}

// ================== gates GEMM: 3-buffer counted-vmcnt + 2-phase compute ==========
__global__ void __launch_bounds__(256) k_gates(
    const _Float16* __restrict__ xh, const _Float16* __restrict__ xl,
    const _Float16* __restrict__ hih, const _Float16* __restrict__ hil,
    const _Float16* __restrict__ wph, const _Float16* __restrict__ wpl,
    const _Float16* __restrict__ vph, const _Float16* __restrict__ vpl,
    const float* __restrict__ biasp, float* __restrict__ c,
    _Float16* __restrict__ hoh, _Float16* __restrict__ hol) {
  extern __shared__ __align__(16) char smem[];
  int tid = threadIdx.x;
  f32x4 acch[4][2] = {};
  f32x4 accc[4][2] = {};
  int x8 = blockIdx.x & 7, q = blockIdx.x >> 3;          // grid 256
  int bn = (((q & 3) << 3) | x8) << 6;
  int bm = (q >> 2) << 7;
  int lane = tid & 63, wv = tid >> 6;
  int wr = (wv >> 1) << 6, wc = (wv & 1) << 5;
  int fr = lane & 15, c0 = lane >> 4;
  int rsub = lane >> 2, cp = lane & 3;
  int psw = (c0 ^ ((fr >> 1) & 3)) << 3;

  auto stage = [&](int p, int t) {
    const _Float16* As_h = (t < 16) ? xh : hih;
    const _Float16* As_l = (t < 16) ? xl : hil;
    const _Float16* Bs_h = (t < 16) ? wph : vph;
    const _Float16* Bs_l = (t < 16) ? wpl : vpl;
    int k0 = (t & 15) << 5;
    char* base = smem + p * 24576;
#pragma unroll
    for (int s = 0; s < 2; ++s) {
      int row = (((wv << 1) + s) << 4) + rsub;
      int koff = (cp ^ ((row >> 1) & 3)) << 3;
      size_t ga = (size_t)(bm + row) * 512 + k0 + koff;
      int lo = (row << 5) + (cp << 3);
      gload16((_Float16*)base + lo, As_h + ga);
      gload16((_Float16*)(base + 8192) + lo, As_l + ga);
    }
    {
      int row = (wv << 4) + rsub;  // 0..63
      int koff = (cp ^ ((row >> 1) & 3)) << 3;
      size_t gb = (size_t)(bn + row) * 512 + k0 + koff;
      int lo = (row << 5) + (cp << 3);
      gload16((_Float16*)(base + 16384) + lo, Bs_h + gb);
      gload16((_Float16*)(base + 20480) + lo, Bs_l + gb);
    }
  };
  auto compute = [&](int p) {
    char* base = smem + p * 24576;
    _Float16 (*Ah)[32] = (_Float16(*)[32])base;
    _Float16 (*Al)[32] = (_Float16(*)[32])(base + 8192);
    _Float16 (*Bh)[32] = (_Float16(*)[32])(base + 16384);
    _Float16 (*Bl)[32] = (_Float16(*)[32])(base + 20480);
    half8 ah[4], al[4];
#pragma unroll
    for (int i = 0; i < 4; ++i) {
      int ra = wr + i * 16 + fr;
      ah[i] = *(const half8*)&Ah[ra][psw];
      al[i] = *(const half8*)&Al[ra][psw];
    }
    SCHEDB();
#pragma unroll
    for (int ni = 0; ni < 2; ++ni) {
      int rb = wc + ni * 16 + fr;
      half8 bh = *(const half8*)&Bh[rb][psw];
      half8 bl = *(const half8*)&Bl[rb][psw];
      __builtin_amdgcn_s_setprio(1);
#pragma unroll
      for (int mi = 0; mi < 4; ++mi) {
        acch[mi][ni] = __builtin_amdgcn_mfma_f32_16x16x32_f16(ah[mi], bh, acch[mi][ni], 0, 0, 0);
        accc[mi][ni] = __builtin_amdgcn_mfma_f32_16x16x32_f16(ah[mi], bl, accc[mi][ni], 0, 0, 0);
        accc[mi][ni] = __builtin_amdgcn_mfma_f32_16x16x32_f16(al[mi], bh, accc[mi][ni], 0, 0, 0);
      }
      __builtin_amdgcn_s_setprio(0);
      SCHEDB();
    }
  };

  stage(0, 0); stage(1, 1);
  asm volatile("s_waitcnt vmcnt(6)" ::: "memory");
  SCHEDB(); SBAR(); SCHEDB();
  int pc = 0, ps = 2;
  for (int t = 0; t < 32; ++t) {
    if (t + 2 < 32) stage(ps, t + 2);
    compute(pc);
    SCHEDB();
    if (t + 2 < 32) { asm volatile("s_waitcnt vmcnt(6) lgkmcnt(0)" ::: "memory"); }
    else            { asm volatile("s_waitcnt vmcnt(0) lgkmcnt(0)" ::: "memory"); }
    SCHEDB(); SBAR(); SCHEDB();
    pc = (pc == 2) ? 0 : pc + 1;
    ps = (ps == 2) ? 0 : ps + 1;
  }

  float (*gtile)[68] = (float(*)[68])smem;
  int orow = (lane >> 4) << 2, ocol = lane & 15;
#pragma unroll
  for (int mi = 0; mi < 4; ++mi)
#pragma unroll
    for (int ni = 0; ni < 2; ++ni) {
      int col = wc + ni * 16 + ocol;
      float bsum = biasp[bn + col];
#pragma unroll
      for (int r = 0; r < 4; ++r) {
        int row = wr + mi * 16 + orow + r;
        gtile[row][col] = acch[mi][ni][r] + accc[mi][ni][r] * (1.0f / 2048.0f) + bsum;
      }
    }
  __syncthreads();
  cell_update(gtile, tid, bm, bn >> 2, c, hoh, hol);
}

// ================== logits GEMM: 256x128, 512 thr, 3-buf counted + 4-phase ========
__global__ void __launch_bounds__(512) k_logits(
    const _Float16* __restrict__ hh, const _Float16* __restrict__ hl,
    const _Float16* __restrict__ outwh, const _Float16* __restrict__ outwl,
    const float* __restrict__ outb, float* __restrict__ logits) {
  extern __shared__ __align__(16) char smem[];
  int tid = threadIdx.x;
  f32x4 acch[4][4] = {};
  f32x4 accc[4][4] = {};
  int x8 = blockIdx.x & 7, q = blockIdx.x >> 3;          // grid 256
  int bn = (((q & 7) << 3) | x8) << 7;                   // 64 n-blocks of 128
  int bm = (q >> 3) << 8;                                // 4 m-blocks of 256
  int lane = tid & 63, wv = tid >> 6;                    // 8 waves
  int wr = (wv >> 1) << 6, wc = (wv & 1) << 6;
  int fr = lane & 15, c0 = lane >> 4;
  int rsub = lane >> 2, cp = lane & 3;
  int psw = (c0 ^ ((fr >> 1) & 3)) << 3;

  auto stage = [&](int p, int t) {
    int k0 = t << 5;
    char* base = smem + p * 49152;
#pragma unroll
    for (int s = 0; s < 2; ++s) {
      int row = (((wv << 1) + s) << 4) + rsub;           // 0..255
      int koff = (cp ^ ((row >> 1) & 3)) << 3;
      size_t ga = (size_t)(bm + row) * 512 + k0 + koff;
      int lo = (row << 5) + (cp << 3);
      gload16((_Float16*)base + lo, hh + ga);
      gload16((_Float16*)(base + 16384) + lo, hl + ga);
    }
    {
      int row = tid >> 2;                                 // 0..127
      int koff = (cp ^ ((row >> 1) & 3)) << 3;
      size_t gb = (size_t)(bn + row) * 512 + k0 + koff;
      int lo = (row << 5) + (cp << 3);
      gload16((_Float16*)(base + 32768) + lo, outwh + gb);
      gload16((_Float16*)(base + 40960) + lo, outwl + gb);
    }
  };
  auto compute = [&](int p) {
    char* base = smem + p * 49152;
    _Float16 (*Ah)[32] = (_Float16(*)[32])base;
    _Float16 (*Al)[32] = (_Float16(*)[32])(base + 16384);
    _Float16 (*Bh)[32] = (_Float16(*)[32])(base + 32768);
    _Float16 (*Bl)[32] = (_Float16(*)[32])(base + 40960);
    half8 ah[4], al[4];
#pragma unroll
    for (int i = 0; i < 4; ++i) {
      int ra = wr + i * 16 + fr;
      ah[i] = *(const half8*)&Ah[ra][psw];
      al[i] = *(const half8*)&Al[ra][psw];
    }
    SCHEDB();
#pragma unroll
    for (int ni = 0; ni < 4; ++ni) {
      int rb = wc + ni * 16 + fr;
      half8 bh = *(const half8*)&Bh[rb][psw];
      half8 bl = *(const half8*)&Bl[rb][psw];
      __builtin_amdgcn_s_setprio(1);
#pragma unroll
      for (int mi = 0; mi < 4; ++mi) {
        acch[mi][ni] = __builtin_amdgcn_mfma_f32_16x16x32_f16(ah[mi], bh, acch[mi][ni], 0, 0, 0);
        accc[mi][ni] = __builtin_amdgcn_mfma_f32_16x16x32_f16(ah[mi], bl, accc[mi][ni], 0, 0, 0);
        accc[mi][ni] = __builtin_amdgcn_mfma_f32_16x16x32_f16(al[mi], bh, accc[mi][ni], 0, 0, 0);
      }
      __builtin_amdgcn_s_setprio(0);
      SCHEDB();
    }
  };

  stage(0, 0); stage(1, 1);
  asm volatile("s_waitcnt vmcnt(6)" ::: "memory");
  SCHEDB(); SBAR(); SCHEDB();
  int pc = 0, ps = 2;
  for (int t = 0; t < 16; ++t) {
    if (t + 2 < 16) stage(ps, t + 2);
    compute(pc);
    SCHEDB();
    if (t + 2 < 16) { asm volatile("s_waitcnt vmcnt(6) lgkmcnt(0)" ::: "memory"); }
    else            { asm volatile("s_waitcnt vmcnt(0) lgkmcnt(0)" ::: "memory"); }
    SCHEDB(); SBAR(); SCHEDB();
    pc = (pc == 2) ? 0 : pc + 1;
    ps = (ps == 2) ? 0 : ps + 1;
  }

  int orow = (lane >> 4) << 2, ocol = lane & 15;
#pragma unroll
  for (int mi = 0; mi < 4; ++mi)
#pragma unroll
    for (int ni = 0; ni < 4; ++ni) {
      int colg = bn + wc + ni * 16 + ocol;
      float bv = outb[colg];
#pragma unroll
      for (int r = 0; r < 4; ++r) {
        int rowg = bm + wr + mi * 16 + orow + r;
        logits[(size_t)rowg * Vn + colg] =
            acch[mi][ni][r] + accc[mi][ni][r] * (1.0f / 2048.0f) + bv;
      }
    }
}

// ================== FALLBACK kernels (R8-proven, static <=64KB LDS) ==================
__global__ void __launch_bounds__(256) k_gates_fb(
    const _Float16* __restrict__ xh, const _Float16* __restrict__ xl,
    const _Float16* __restrict__ hih, const _Float16* __restrict__ hil,
    const _Float16* __restrict__ wph, const _Float16* __restrict__ wpl,
    const _Float16* __restrict__ vph, const _Float16* __restrict__ vpl,
    const float* __restrict__ biasp, float* __restrict__ c,
    _Float16* __restrict__ hoh, _Float16* __restrict__ hol) {
  __shared__ __align__(16) char smem[49152];
  int tid = threadIdx.x;
  f32x4 acch[4][2] = {};
  f32x4 accc[4][2] = {};
  int x8 = blockIdx.x & 7, q = blockIdx.x >> 3;
  int bn = (((q & 3) << 3) | x8) << 6;
  int bm = (q >> 2) << 7;
  int lane = tid & 63, wv = tid >> 6;
  int wr = (wv >> 1) << 6, wc = (wv & 1) << 5;
  int fr = lane & 15, c0 = lane >> 4;
  int rsub = lane >> 2, cp = lane & 3;
  int psw = (c0 ^ ((fr >> 1) & 3)) << 3;
  auto stage = [&](int p, int t) {
    const _Float16* As_h = (t < 16) ? xh : hih;
    const _Float16* As_l = (t < 16) ? xl : hil;
    const _Float16* Bs_h = (t < 16) ? wph : vph;
    const _Float16* Bs_l = (t < 16) ? wpl : vpl;
    int k0 = (t & 15) << 5;
    char* base = smem + p * 24576;
#pragma unroll
    for (int s = 0; s < 2; ++s) {
      int row = (((wv << 1) + s) << 4) + rsub;
      int koff = (cp ^ ((row >> 1) & 3)) << 3;
      size_t ga = (size_t)(bm + row) * 512 + k0 + koff;
      int lo = (row << 5) + (cp << 3);
      gload16((_Float16*)base + lo, As_h + ga);
      gload16((_Float16*)(base + 8192) + lo, As_l + ga);
    }
    {
      int row = (wv << 4) + rsub;
      int koff = (cp ^ ((row >> 1) & 3)) << 3;
      size_t gb = (size_t)(bn + row) * 512 + k0 + koff;
      int lo = (row << 5) + (cp << 3);
      gload16((_Float16*)(base + 16384) + lo, Bs_h + gb);
      gload16((_Float16*)(base + 20480) + lo, Bs_l + gb);
    }
  };
  auto compute = [&](int p) {
    char* base = smem + p * 24576;
    _Float16 (*Ah)[32] = (_Float16(*)[32])base;
    _Float16 (*Al)[32] = (_Float16(*)[32])(base + 8192);
    _Float16 (*Bh)[32] = (_Float16(*)[32])(base + 16384);
    _Float16 (*Bl)[32] = (_Float16(*)[32])(base + 20480);
    half8 ah[4], al[4], bh[2], bl[2];
#pragma unroll
    for (int i = 0; i < 4; ++i) {
      int ra = wr + i * 16 + fr;
      ah[i] = *(const half8*)&Ah[ra][psw];
      al[i] = *(const half8*)&Al[ra][psw];
    }
#pragma unroll
    for (int i = 0; i < 2; ++i) {
      int rb = wc + i * 16 + fr;
      bh[i] = *(const half8*)&Bh[rb][psw];
      bl[i] = *(const half8*)&Bl[rb][psw];
    }
#pragma unroll
    for (int mi = 0; mi < 4; ++mi)
#pragma unroll
      for (int ni = 0; ni < 2; ++ni) {
        acch[mi][ni] = __builtin_amdgcn_mfma_f32_16x16x32_f16(ah[mi], bh[ni], acch[mi][ni], 0, 0, 0);
        accc[mi][ni] = __builtin_amdgcn_mfma_f32_16x16x32_f16(ah[mi], bl[ni], accc[mi][ni], 0, 0, 0);
        accc[mi][ni] = __builtin_amdgcn_mfma_f32_16x16x32_f16(al[mi], bh[ni], accc[mi][ni], 0, 0, 0);
      }
  };
  stage(0, 0); stage(1, 1);
  asm volatile("s_waitcnt vmcnt(6)" ::: "memory");
  SCHEDB(); SBAR(); SCHEDB();
  int pc = 0, ps = 2;
  for (int t = 0; t < 32; ++t) {
    if (t + 2 < 32) stage(ps, t + 2);
    compute(pc);
    SCHEDB();
    if (t + 2 < 32) { asm volatile("s_waitcnt vmcnt(6) lgkmcnt(0)" ::: "memory"); }
    else            { asm volatile("s_waitcnt vmcnt(0) lgkmcnt(0)" ::: "memory"); }
    SCHEDB(); SBAR(); SCHEDB();
    pc = (pc == 2) ? 0 : pc + 1;
    ps = (ps == 2) ? 0 : ps + 1;
  }
  float (*gtile)[68] = (float(*)[68])smem;
  int orow = (lane >> 4) << 2, ocol = lane & 15;
#pragma unroll
  for (int mi = 0; mi < 4; ++mi)
#pragma unroll
    for (int ni = 0; ni < 2; ++ni) {
      int col = wc + ni * 16 + ocol;
      float bsum = biasp[bn + col];
#pragma unroll
      for (int r = 0; r < 4; ++r) {
        int row = wr + mi * 16 + orow + r;
        gtile[row][col] = acch[mi][ni][r] + accc[mi][ni][r] * (1.0f / 2048.0f) + bsum;
      }
    }
  __syncthreads();
  cell_update(gtile, tid, bm, bn >> 2, c, hoh, hol);
}

__global__ void __launch_bounds__(256) k_logits_fb(
    const _Float16* __restrict__ hh, const _Float16* __restrict__ hl,
    const _Float16* __restrict__ outwh, const _Float16* __restrict__ outwl,
    const float* __restrict__ outb, float* __restrict__ logits) {
  __shared__ __align__(16) char smem[65536];
  int tid = threadIdx.x;
  f32x4 acch[4][4] = {};
  f32x4 accc[4][4] = {};
  int x8 = blockIdx.x & 7, q = blockIdx.x >> 3;          // grid 512
  int bn = (((q & 7) << 3) | x8) << 7;
  int bm = (q >> 3) << 7;
  int lane = tid & 63, wv = tid >> 6;
  int wr = (wv >> 1) << 6, wc = (wv & 1) << 6;
  int fr = lane & 15, c0 = lane >> 4;
  int rsub = lane >> 2, cp = lane & 3;
  int psw = (c0 ^ ((fr >> 1) & 3)) << 3;
  auto stage = [&](int p, int t) {
    int k0 = t << 5;
    char* base = smem + (p << 15);
#pragma unroll
    for (int s = 0; s < 2; ++s) {
      int row = (((wv << 1) + s) << 4) + rsub;
      int koff = (cp ^ ((row >> 1) & 3)) << 3;
      size_t ga = (size_t)(bm + row) * 512 + k0 + koff;
      size_t gb = (size_t)(bn + row) * 512 + k0 + koff;
      int lo = (row << 5) + (cp << 3);
      gload16((_Float16*)base + lo, hh + ga);
      gload16((_Float16*)(base + 8192) + lo, hl + ga);
      gload16((_Float16*)(base + 16384) + lo, outwh + gb);
      gload16((_Float16*)(base + 24576) + lo, outwl + gb);
    }
  };
  auto compute = [&](int p) {
    char* base = smem + (p << 15);
    _Float16 (*Ah)[32] = (_Float16(*)[32])base;
    _Float16 (*Al)[32] = (_Float16(*)[32])(base + 8192);
    _Float16 (*Bh)[32] = (_Float16(*)[32])(base + 16384);
    _Float16 (*Bl)[32] = (_Float16(*)[32])(base + 24576);
    half8 ah[4], al[4], bh[4], bl[4];
#pragma unroll
    for (int i = 0; i < 4; ++i) {
      int ra = wr + i * 16 + fr;
      int rb = wc + i * 16 + fr;
      ah[i] = *(const half8*)&Ah[ra][psw];
      al[i] = *(const half8*)&Al[ra][psw];
      bh[i] = *(const half8*)&Bh[rb][psw];
      bl[i] = *(const half8*)&Bl[rb][psw];
    }
#pragma unroll
    for (int mi = 0; mi < 4; ++mi)
#pragma unroll
      for (int ni = 0; ni < 4; ++ni) {
        acch[mi][ni] = __builtin_amdgcn_mfma_f32_16x16x32_f16(ah[mi], bh[ni], acch[mi][ni], 0, 0, 0);
        accc[mi][ni] = __builtin_amdgcn_mfma_f32_16x16x32_f16(ah[mi], bl[ni], accc[mi][ni], 0, 0, 0);
        accc[mi][ni] = __builtin_amdgcn_mfma_f32_16x16x32_f16(al[mi], bh[ni], accc[mi][ni], 0, 0, 0);
      }
  };
  stage(0, 0);
  __syncthreads();
  int cur = 0;
  for (int t = 0; t < 16; ++t) {
    if (t + 1 < 16) stage(cur ^ 1, t + 1);
    compute(cur);
    __syncthreads();
    cur ^= 1;
  }
  int orow = (lane >> 4) << 2, ocol = lane & 15;
#pragma unroll
  for (int mi = 0; mi < 4; ++mi)
#pragma unroll
    for (int ni = 0; ni < 4; ++ni) {
      int colg = bn + wc + ni * 16 + ocol;
      float bv = outb[colg];
#pragma unroll
      for (int r = 0; r < 4; ++r) {
        int rowg = bm + wr + mi * 16 + orow + r;
        logits[(size_t)rowg * Vn + colg] =
            acch[mi][ni][r] + accc[mi][ni][r] * (1.0f / 2048.0f) + bv;
      }
    }
}

// ---------------- f32 register-tiled GEMM (k_fc1 only, runs once) ----------
__device__ __forceinline__ void gemm_seg(
    const float* __restrict__ A, int lda, const float* __restrict__ W, int ldw,
    int bm, int bn, int tid, int tm8, int tn4,
    float (*As)[132], float (*Bs)[68], float acc[8][4]) {
  for (int k0 = 0; k0 < 512; k0 += 16) {
#pragma unroll
    for (int it = 0; it < 2; ++it) {
      int g = (it << 8) + tid;
      int m = g >> 2, kq = g & 3;
      const float4 v = *(const float4*)(A + (size_t)(bm + m) * lda + k0 + (kq << 2));
      As[(kq << 2) + 0][m] = v.x; As[(kq << 2) + 1][m] = v.y;
      As[(kq << 2) + 2][m] = v.z; As[(kq << 2) + 3][m] = v.w;
    }
    {
      int m = tid >> 2, kq = tid & 3;
      const float4 v = *(const float4*)(W + (size_t)(bn + m) * ldw + k0 + (kq << 2));
      Bs[(kq << 2) + 0][m] = v.x; Bs[(kq << 2) + 1][m] = v.y;
      Bs[(kq << 2) + 2][m] = v.z; Bs[(kq << 2) + 3][m] = v.w;
    }
    __syncthreads();
#pragma unroll
    for (int k = 0; k < 16; ++k) {
      const float4 a0 = *(const float4*)&As[k][tm8];
      const float4 a1 = *(const float4*)&As[k][tm8 + 4];
      const float4 bv = *(const float4*)&Bs[k][tn4];
      float av[8] = {a0.x, a0.y, a0.z, a0.w, a1.x, a1.y, a1.z, a1.w};
      float bw[4] = {bv.x, bv.y, bv.z, bv.w};
#pragma unroll
      for (int i = 0; i < 8; ++i)
#pragma unroll
        for (int j = 0; j < 4; ++j)
          acc[i][j] = fmaf(av[i], bw[j], acc[i][j]);
    }
    __syncthreads();
  }
}

// ---------------- init: h0 = relu(img@fc1^T + b) -> hh/hl; c=0; x=0 --------
__global__ void __launch_bounds__(256) k_fc1(
    const float* __restrict__ img, const float* __restrict__ fc1w,
    const float* __restrict__ fc1b,
    _Float16* __restrict__ hh, _Float16* __restrict__ hl,
    _Float16* __restrict__ xh, _Float16* __restrict__ xl,
    float* __restrict__ c) {
  __shared__ float As[16][132];
  __shared__ float Bs[16][68];
  int tid = threadIdx.x;
  int tm8 = (tid >> 4) << 3;
  int tn4 = (tid & 15) << 2;
  float acc[8][4] = {};
  int bm = (blockIdx.x >> 3) << 7;
  int bn = (blockIdx.x & 7) << 6;
  gemm_seg(img, Dn, fc1w, Dn, bm, bn, tid, tm8, tn4, As, Bs, acc);
  const float4 b4 = *(const float4*)(fc1b + bn + tn4);
  float bb[4] = {b4.x, b4.y, b4.z, b4.w};
#pragma unroll
  for (int i = 0; i < 8; ++i) {
    size_t off = (size_t)(bm + tm8 + i) * Hn + bn + tn4;
#pragma unroll
    for (int j = 0; j < 4; ++j) {
      float hv = fmaxf(acc[i][j] + bb[j], 0.f);
      split16(hv, hh[off + j], hl[off + j]);
      xh[off + j] = (_Float16)0.f;
      xl[off + j] = (_Float16)0.f;
      c[off + j] = 0.f;
    }
  }
}

// ---------------- fused softmax + gumbel-argmax + outputs + next-x ---------
// Partitionable threefry: bits(j) = y0 ^ y1, (y0,y1) = threefry(step_key, 0, j), j = b*V+v.
// Native __logf/__expf validated R11/R12 (identical sampling, absmax 1.9e-6).
// Entropy folded into pass 2: ent = lse - T/S, T = sum e^sh * sh.
__global__ void __launch_bounds__(256) k_sm(
    const float* __restrict__ logits, const float* __restrict__ emb,
    float* __restrict__ mask, float* __restrict__ out_base,
    _Float16* __restrict__ xh, _Float16* __restrict__ xl,
    unsigned k0, unsigned k1, int t) {
  __shared__ __align__(16) float row[Vn];
  __shared__ float rf[256];
  __shared__ int ri[256];
  __shared__ double rd[256];
  __shared__ double rt[256];
  int b = blockIdx.x, tid = threadIdx.x;
  const float4* src = (const float4*)(logits + (size_t)b * Vn);
  float4* dst = (float4*)row;
  for (int i = tid; i < Vn / 4; i += 256) dst[i] = src[i];
  __syncthreads();

  // pass 1: row max + gumbel argmax (first-index tiebreak)
  float m = -INFINITY, best = -INFINITY;
  int bidx = Vn;
  for (int v = tid; v < Vn; v += 256) {
    float lg = row[v];
    m = fmaxf(m, lg);
    unsigned j = (unsigned)(b * Vn + v);
    unsigned y0, y1;
    threefry2x32(k0, k1, 0u, j, y0, y1);
    unsigned bits = y0 ^ y1;
    float uf = fmaxf(__uint_as_float((bits >> 9) | 0x3F800000u) - 1.0f,
                     1.17549435e-38f);
    float g = -__logf(-__logf(uf));
    float val = lg + g;
    if (val > best) { best = val; bidx = v; }   // ascending v -> first max kept
  }
  rf[tid] = m;
  __syncthreads();
  for (int s = 128; s > 0; s >>= 1) {
    if (tid < s) rf[tid] = fmaxf(rf[tid], rf[tid + s]);
    __syncthreads();
  }
  float rowmax = rf[0];
  __syncthreads();
  rf[tid] = best; ri[tid] = bidx;
  __syncthreads();
  for (int s = 128; s > 0; s >>= 1) {
    if (tid < s) {
      float v2 = rf[tid + s]; int i2 = ri[tid + s];
      if (v2 > rf[tid] || (v2 == rf[tid] && i2 < ri[tid])) { rf[tid] = v2; ri[tid] = i2; }
    }
    __syncthreads();
  }
  int act = ri[0];

  // pass 2: S = sum e^sh, T = sum e^sh * sh (f64 adds)
  double sacc = 0.0, tacc = 0.0;
  for (int v = tid; v < Vn; v += 256) {
    float sh = row[v] - rowmax;
    float e = __expf(sh);
    sacc += (double)e;
    tacc += (double)(e * sh);
  }
  rd[tid] = sacc; rt[tid] = tacc;
  __syncthreads();
  for (int s = 128; s > 0; s >>= 1) {
    if (tid < s) { rd[tid] += rd[tid + s]; rt[tid] += rt[tid + s]; }
    __syncthreads();
  }
  double S = rd[0], T = rt[0];
  double lse = log(S);
  float mk = mask[b];

  // pass 3 (float4): probs + lps
  float* probs = out_base + 3 * Bn * Tn + ((size_t)(b * Tn + t)) * Vn;
  for (int v0 = tid << 2; v0 < Vn; v0 += 1024) {
    float4 l4 = *(const float4*)&row[v0];
    float lp[4];
    lp[0] = (float)((double)(l4.x - rowmax) - lse);
    lp[1] = (float)((double)(l4.y - rowmax) - lse);
    lp[2] = (float)((double)(l4.z - rowmax) - lse);
    lp[3] = (float)((double)(l4.w - rowmax) - lse);
    float4 o = {__expf(lp[0]) * mk, __expf(lp[1]) * mk,
                __expf(lp[2]) * mk, __expf(lp[3]) * mk};
    *(float4*)&probs[v0] = o;
    int d = act - v0;
    if (d >= 0 && d < 4)
      out_base[Bn * Tn + b * Tn + t] = lp[d] * mk;  // lps
  }
  // fused next-input: x = emb[act] (split), mask update (eos=0)
  for (int j = tid; j < Hn; j += 256) {
    float v = emb[(size_t)act * Hn + j];
    split16(v, xh[(size_t)b * Hn + j], xl[(size_t)b * Hn + j]);
  }
  if (tid == 0) {
    out_base[2 * Bn * Tn + b * Tn + t] = (float)(lse - T / S) * mk;  // ents
    out_base[b * Tn + t] = (float)act;                               // msgs
    mask[b] = mk * (act == 0 ? 0.f : 1.f);
  }
}

extern "C" void kernel_launch(void* const* d_in, const int* in_sizes, int n_in,
                              void* d_out, int out_size, void* d_ws, size_t ws_size,
                              hipStream_t stream) {
  const float* img  = (const float*)d_in[0];
  const float* emb  = (const float*)d_in[1];
  const float* fc1w = (const float*)d_in[2];
  const float* fc1b = (const float*)d_in[3];
  const float* wih  = (const float*)d_in[4];
  const float* whh  = (const float*)d_in[5];
  const float* bih  = (const float*)d_in[6];
  const float* bhh  = (const float*)d_in[7];
  const float* outw = (const float*)d_in[8];
  const float* outb = (const float*)d_in[9];
  float* out = (float*)d_out;

  float* ws = (float*)d_ws;
  float* c      = ws;                          // B*H
  float* mask   = c + Bn * Hn;                 // B
  float* biasp  = mask + Bn;                   // G4
  float* logits = biasp + G4;                  // B*V
  _Float16* wph  = (_Float16*)(logits + (size_t)Bn * Vn);  // permuted wih hi
  _Float16* wpl  = wph + (size_t)G4 * Hn;
  _Float16* vph  = wpl + (size_t)G4 * Hn;                  // permuted whh hi
  _Float16* vpl  = vph + (size_t)G4 * Hn;
  _Float16* outwh = vpl + (size_t)G4 * Hn;
  _Float16* outwl = outwh + (size_t)Vn * Hn;
  _Float16* xh = outwl + (size_t)Vn * Hn;
  _Float16* xl = xh + Bn * Hn;
  _Float16* hhA = xl + Bn * Hn;
  _Float16* hlA = hhA + Bn * Hn;
  _Float16* hhB = hlA + Bn * Hn;
  _Float16* hlB = hhB + Bn * Hn;

  // step keys: fold-like split (jax_threefry_partitionable):
  // keys[t] = threefry2x32(key=(0,42), x0=0, x1=t)
  unsigned kk0[Tn], kk1[Tn];
  for (int i = 0; i < Tn; ++i) {
    unsigned y0, y1;
    threefry2x32(0u, 42u, 0u, (unsigned)i, y0, y1);
    kk0[i] = y0; kk1[i] = y1;
  }

  // dynamic-LDS opt-in (>64KB). Non-stream calls; graph-capture safe. If the
  // stack rejects them, fall back to the proven static-LDS kernels.
  bool big_lds =
      (hipFuncSetAttribute((const void*)k_gates,
                           hipFuncAttributeMaxDynamicSharedMemorySize, 73728) == hipSuccess) &&
      (hipFuncSetAttribute((const void*)k_logits,
                           hipFuncAttributeMaxDynamicSharedMemorySize, 147456) == hipSuccess);

  // one-time preps
  k_prep_perm<<<(G4 * Hn) / 256, 256, 0, stream>>>(wih, wph, wpl);
  k_prep_perm<<<(G4 * Hn) / 256, 256, 0, stream>>>(whh, vph, vpl);
  k_prep<<<(Vn * Hn) / 256, 256, 0, stream>>>(outw, outwh, outwl, Vn * Hn);
  k_prep_bias<<<G4 / 256, 256, 0, stream>>>(bih, bhh, biasp);
  k_mask<<<4, 256, 0, stream>>>(mask);
  k_fc1<<<64, 256, 0, stream>>>(img, fc1w, fc1b, hhA, hlA, xh, xl, c);

  for (int t = 0; t < Tn; ++t) {
    const _Float16* hih = (t & 1) ? hhB : hhA;
    const _Float16* hil = (t & 1) ? hlB : hlA;
    _Float16* hoh = (t & 1) ? hhA : hhB;
    _Float16* hol = (t & 1) ? hlA : hlB;
    if (big_lds) {
      k_gates<<<256, 256, 73728, stream>>>(
          xh, xl, hih, hil, wph, wpl, vph, vpl, biasp, c, hoh, hol);
      k_logits<<<256, 512, 147456, stream>>>(
          hoh, hol, outwh, outwl, outb, logits);
    } else {
      k_gates_fb<<<256, 256, 0, stream>>>(
          xh, xl, hih, hil, wph, wpl, vph, vpl, biasp, c, hoh, hol);
      k_logits_fb<<<512, 256, 0, stream>>>(
          hoh, hol, outwh, outwl, outb, logits);
    }
    k_sm<<<Bn, 256, 0, stream>>>(logits, emb, mask, out, xh, xl, kk0[t], kk1[t], t);
  }
}

// Round 14
// 1955.224 us; speedup vs baseline: 1.0410x; 1.0410x over previous
//
#include <hip/hip_runtime.h>
#include <math.h>

#define Bn 1024
#define Dn 512
#define Hn 512
#define Vn 8192
#define Tn 20
#define G4 2048

typedef _Float16 half8 __attribute__((ext_vector_type(8)));
typedef float f32x4 __attribute__((ext_vector_type(4)));

#define SCHEDB() __builtin_amdgcn_sched_barrier(0)
#define SBAR()   __builtin_amdgcn_s_barrier()

// ---------------- threefry2x32 (JAX-exact, 20 rounds) ----------------
__host__ __device__ __forceinline__ void threefry2x32(
    unsigned k0, unsigned k1, unsigned x0, unsigned x1,
    unsigned& y0, unsigned& y1) {
  unsigned ks2 = k0 ^ k1 ^ 0x1BD11BDAu;
#define TF_RND(r) { x0 += x1; x1 = (x1 << (r)) | (x1 >> (32 - (r))); x1 ^= x0; }
  x0 += k0; x1 += k1;
  TF_RND(13) TF_RND(15) TF_RND(26) TF_RND(6)
  x0 += k1; x1 += ks2 + 1u;
  TF_RND(17) TF_RND(29) TF_RND(16) TF_RND(24)
  x0 += ks2; x1 += k0 + 2u;
  TF_RND(13) TF_RND(15) TF_RND(26) TF_RND(6)
  x0 += k0; x1 += k1 + 3u;
  TF_RND(17) TF_RND(29) TF_RND(16) TF_RND(24)
  x0 += k1; x1 += ks2 + 4u;
  TF_RND(13) TF_RND(15) TF_RND(26) TF_RND(6)
  x0 += ks2; x1 += k0 + 5u;
#undef TF_RND
  y0 = x0; y1 = x1;
}

// f32 -> f16 hi/lo split. lo scaled by 2^11 to stay in f16 normal range.
__device__ __forceinline__ void split16(float v, _Float16& hi, _Float16& lo) {
  float h = (fabsf(v) < 6.2e-5f) ? 0.f : (float)(_Float16)v;  // keep hi out of f16-denorm
  hi = (_Float16)h;
  lo = (_Float16)((v - h) * 2048.0f);
}

// async 16B global->LDS. HW dest = wave-uniform base + lane*16; our per-lane
// addressing (row=f(lane>>2), chunk=lane&3) equals exactly that mapping.
__device__ __forceinline__ void gload16(void* l, const void* g) {
  __builtin_amdgcn_global_load_lds(
      (const __attribute__((address_space(1))) unsigned int*)g,
      (__attribute__((address_space(3))) unsigned int*)l, 16, 0, 0);
}

// ---------------- prep kernels (run every call; idempotent) ----------------
__global__ void k_prep(const float* __restrict__ w, _Float16* __restrict__ hi,
                       _Float16* __restrict__ lo, int n) {
  int i = blockIdx.x * blockDim.x + threadIdx.x;
  if (i >= n) return;
  split16(w[i], hi[i], lo[i]);
}

// gate-interleaved permutation: dst row u*4+g  <-  src row g*512+u
__global__ void k_prep_perm(const float* __restrict__ w, _Float16* __restrict__ hi,
                            _Float16* __restrict__ lo) {
  int i = blockIdx.x * blockDim.x + threadIdx.x;  // G4*Hn
  int rp = i >> 9, k = i & 511;
  int u = rp >> 2, g = rp & 3;
  split16(w[(size_t)((g << 9) + u) * 512 + k], hi[i], lo[i]);
}

__global__ void k_prep_bias(const float* __restrict__ bih, const float* __restrict__ bhh,
                            float* __restrict__ bp) {
  int i = blockIdx.x * blockDim.x + threadIdx.x;  // G4
  if (i >= G4) return;
  int u = i >> 2, g = i & 3;
  bp[i] = bih[(g << 9) + u] + bhh[(g << 9) + u];
}

__global__ void k_mask(float* __restrict__ mask) {
  int i = blockIdx.x * blockDim.x + threadIdx.x;
  if (i < Bn) mask[i] = 1.f;
}

// ================== gates GEMM: 8-wave 128x64, 3-buf counted vmcnt(3) ==================
// Wave grid 2M x 4N (per-wave 64x16 output, acc[4]x1). Layout HW-validated in R10
// (bit-identical output). 512 threads -> 8 waves/CU for latency hiding.
__global__ void __launch_bounds__(512) k_gates(
    const _Float16* __restrict__ xh, const _Float16* __restrict__ xl,
    const _Float16* __restrict__ hih, const _Float16* __restrict__ hil,
    const _Float16* __restrict__ wph, const _Float16* __restrict__ wpl,
    const _Float16* __restrict__ vph, const _Float16* __restrict__ vpl,
    const float* __restrict__ biasp, float* __restrict__ c,
    _Float16* __restrict__ hoh, _Float16* __restrict__ hol) {
  extern __shared__ __align__(16) char smem[];
  int tid = threadIdx.x;
  f32x4 acch[4] = {};
  f32x4 accc[4] = {};
  int x8 = blockIdx.x & 7, q = blockIdx.x >> 3;          // grid 256
  int bn = (((q & 3) << 3) | x8) << 6;
  int bm = (q >> 2) << 7;
  int lane = tid & 63, wv = tid >> 6;                    // 8 waves
  int wr = (wv >> 2) << 6, wc = (wv & 3) << 4;           // 2M x 4N
  int fr = lane & 15, c0 = lane >> 4;
  int rsub = lane >> 2, cp = lane & 3;
  int psw = (c0 ^ ((fr >> 1) & 3)) << 3;

  auto stage = [&](int p, int t) {
    const _Float16* As_h = (t < 16) ? xh : hih;
    const _Float16* As_l = (t < 16) ? xl : hil;
    const _Float16* Bs_h = (t < 16) ? wph : vph;
    const _Float16* Bs_l = (t < 16) ? wpl : vpl;
    int k0 = (t & 15) << 5;
    char* base = smem + p * 24576;
    {
      int row = (wv << 4) + rsub;                        // 0..127
      int koff = (cp ^ ((row >> 1) & 3)) << 3;
      size_t ga = (size_t)(bm + row) * 512 + k0 + koff;
      int lo = (row << 5) + (cp << 3);
      gload16((_Float16*)base + lo, As_h + ga);
      gload16((_Float16*)(base + 8192) + lo, As_l + ga);
    }
    {
      int brow = ((wv & 3) << 4) + rsub;                 // 0..63
      int bkoff = (cp ^ ((brow >> 1) & 3)) << 3;
      size_t gb = (size_t)(bn + brow) * 512 + k0 + bkoff;
      int blo = (brow << 5) + (cp << 3);
      if (wv < 4) gload16((_Float16*)(base + 16384) + blo, Bs_h + gb);
      else        gload16((_Float16*)(base + 20480) + blo, Bs_l + gb);
    }
  };
  auto compute = [&](int p) {
    char* base = smem + p * 24576;
    _Float16 (*Ah)[32] = (_Float16(*)[32])base;
    _Float16 (*Al)[32] = (_Float16(*)[32])(base + 8192);
    _Float16 (*Bh)[32] = (_Float16(*)[32])(base + 16384);
    _Float16 (*Bl)[32] = (_Float16(*)[32])(base + 20480);
    half8 ah[4], al[4];
#pragma unroll
    for (int i = 0; i < 4; ++i) {
      int ra = wr + i * 16 + fr;
      ah[i] = *(const half8*)&Ah[ra][psw];
      al[i] = *(const half8*)&Al[ra][psw];
    }
    half8 bh = *(const half8*)&Bh[wc + fr][psw];
    half8 bl = *(const half8*)&Bl[wc + fr][psw];
#pragma unroll
    for (int mi = 0; mi < 4; ++mi) {
      acch[mi] = __builtin_amdgcn_mfma_f32_16x16x32_f16(ah[mi], bh, acch[mi], 0, 0, 0);
      accc[mi] = __builtin_amdgcn_mfma_f32_16x16x32_f16(ah[mi], bl, accc[mi], 0, 0, 0);
      accc[mi] = __builtin_amdgcn_mfma_f32_16x16x32_f16(al[mi], bh, accc[mi], 0, 0, 0);
    }
  };

  stage(0, 0); stage(1, 1);
  asm volatile("s_waitcnt vmcnt(3)" ::: "memory");
  SCHEDB(); SBAR(); SCHEDB();
  int pc = 0, ps = 2;
  for (int t = 0; t < 32; ++t) {
    if (t + 2 < 32) stage(ps, t + 2);
    compute(pc);
    SCHEDB();
    if (t + 2 < 32) { asm volatile("s_waitcnt vmcnt(3) lgkmcnt(0)" ::: "memory"); }
    else            { asm volatile("s_waitcnt vmcnt(0) lgkmcnt(0)" ::: "memory"); }
    SCHEDB(); SBAR(); SCHEDB();
    pc = (pc == 2) ? 0 : pc + 1;
    ps = (ps == 2) ? 0 : ps + 1;
  }

  float (*gtile)[68] = (float(*)[68])smem;
  int orow = (lane >> 4) << 2, ocol = lane & 15;
  {
    int col = wc + ocol;
    float bsum = biasp[bn + col];
#pragma unroll
    for (int mi = 0; mi < 4; ++mi)
#pragma unroll
      for (int r = 0; r < 4; ++r) {
        int row = wr + mi * 16 + orow + r;
        gtile[row][col] = acch[mi][r] + accc[mi][r] * (1.0f / 2048.0f) + bsum;
      }
  }
  __syncthreads();
  // fused cell update, 512 threads: 2048 gate-quads, 4 per thread
  int u0 = bn >> 2;
#pragma unroll
  for (int j = 0; j < 4; ++j) {
    int idx = tid + (j << 9);
    int row = idx >> 4, ul = idx & 15;
    float4 gt = *(const float4*)&gtile[row][ul << 2];  // i,f,g,o
    size_t cidx = (size_t)(bm + row) * Hn + u0 + ul;
    float si = 1.0f / (1.0f + expf(-gt.x));
    float sf = 1.0f / (1.0f + expf(-gt.y));
    float tg = tanhf(gt.z);
    float so = 1.0f / (1.0f + expf(-gt.w));
    float cn = sf * c[cidx] + si * tg;
    c[cidx] = cn;
    float hv = so * tanhf(cn);
    split16(hv, hoh[cidx], hol[cidx]);
  }
}

// ================== logits GEMM: 256x128 tile, 512 thr, 3-buf counted ==================
__global__ void __launch_bounds__(512) k_logits(
    const _Float16* __restrict__ hh, const _Float16* __restrict__ hl,
    const _Float16* __restrict__ outwh, const _Float16* __restrict__ outwl,
    const float* __restrict__ outb, float* __restrict__ logits) {
  extern __shared__ __align__(16) char smem[];
  int tid = threadIdx.x;
  f32x4 acch[4][4] = {};
  f32x4 accc[4][4] = {};
  int x8 = blockIdx.x & 7, q = blockIdx.x >> 3;          // grid 256
  int bn = (((q & 7) << 3) | x8) << 7;                   // 64 n-blocks of 128
  int bm = (q >> 3) << 8;                                // 4 m-blocks of 256
  int lane = tid & 63, wv = tid >> 6;                    // 8 waves
  int wr = (wv >> 1) << 6, wc = (wv & 1) << 6;
  int fr = lane & 15, c0 = lane >> 4;
  int rsub = lane >> 2, cp = lane & 3;
  int psw = (c0 ^ ((fr >> 1) & 3)) << 3;

  auto stage = [&](int p, int t) {
    int k0 = t << 5;
    char* base = smem + p * 49152;
#pragma unroll
    for (int s = 0; s < 2; ++s) {
      int row = (((wv << 1) + s) << 4) + rsub;           // 0..255
      int koff = (cp ^ ((row >> 1) & 3)) << 3;
      size_t ga = (size_t)(bm + row) * 512 + k0 + koff;
      int lo = (row << 5) + (cp << 3);
      gload16((_Float16*)base + lo, hh + ga);
      gload16((_Float16*)(base + 16384) + lo, hl + ga);
    }
    {
      int row = tid >> 2;                                 // 0..127
      int koff = (cp ^ ((row >> 1) & 3)) << 3;
      size_t gb = (size_t)(bn + row) * 512 + k0 + koff;
      int lo = (row << 5) + (cp << 3);
      gload16((_Float16*)(base + 32768) + lo, outwh + gb);
      gload16((_Float16*)(base + 40960) + lo, outwl + gb);
    }
  };
  auto compute = [&](int p) {
    char* base = smem + p * 49152;
    _Float16 (*Ah)[32] = (_Float16(*)[32])base;
    _Float16 (*Al)[32] = (_Float16(*)[32])(base + 16384);
    _Float16 (*Bh)[32] = (_Float16(*)[32])(base + 32768);
    _Float16 (*Bl)[32] = (_Float16(*)[32])(base + 40960);
    half8 ah[4], al[4], bh[4], bl[4];
#pragma unroll
    for (int i = 0; i < 4; ++i) {
      int ra = wr + i * 16 + fr;
      int rb = wc + i * 16 + fr;
      ah[i] = *(const half8*)&Ah[ra][psw];
      al[i] = *(const half8*)&Al[ra][psw];
      bh[i] = *(const half8*)&Bh[rb][psw];
      bl[i] = *(const half8*)&Bl[rb][psw];
    }
#pragma unroll
    for (int mi = 0; mi < 4; ++mi)
#pragma unroll
      for (int ni = 0; ni < 4; ++ni) {
        acch[mi][ni] = __builtin_amdgcn_mfma_f32_16x16x32_f16(ah[mi], bh[ni], acch[mi][ni], 0, 0, 0);
        accc[mi][ni] = __builtin_amdgcn_mfma_f32_16x16x32_f16(ah[mi], bl[ni], accc[mi][ni], 0, 0, 0);
        accc[mi][ni] = __builtin_amdgcn_mfma_f32_16x16x32_f16(al[mi], bh[ni], accc[mi][ni], 0, 0, 0);
      }
  };

  stage(0, 0); stage(1, 1);
  asm volatile("s_waitcnt vmcnt(6)" ::: "memory");
  SCHEDB(); SBAR(); SCHEDB();
  int pc = 0, ps = 2;
  for (int t = 0; t < 16; ++t) {
    if (t + 2 < 16) stage(ps, t + 2);
    compute(pc);
    SCHEDB();
    if (t + 2 < 16) { asm volatile("s_waitcnt vmcnt(6) lgkmcnt(0)" ::: "memory"); }
    else            { asm volatile("s_waitcnt vmcnt(0) lgkmcnt(0)" ::: "memory"); }
    SCHEDB(); SBAR(); SCHEDB();
    pc = (pc == 2) ? 0 : pc + 1;
    ps = (ps == 2) ? 0 : ps + 1;
  }

  int orow = (lane >> 4) << 2, ocol = lane & 15;
#pragma unroll
  for (int mi = 0; mi < 4; ++mi)
#pragma unroll
    for (int ni = 0; ni < 4; ++ni) {
      int colg = bn + wc + ni * 16 + ocol;
      float bv = outb[colg];
#pragma unroll
      for (int r = 0; r < 4; ++r) {
        int rowg = bm + wr + mi * 16 + orow + r;
        logits[(size_t)rowg * Vn + colg] =
            acch[mi][ni][r] + accc[mi][ni][r] * (1.0f / 2048.0f) + bv;
      }
    }
}

// ================== FALLBACK kernels (R8-proven, static <=64KB LDS) ==================
__device__ __forceinline__ void cell_update256(
    float (*gtile)[68], int tid, int bm, int u0, float* __restrict__ c,
    _Float16* __restrict__ hoh, _Float16* __restrict__ hol) {
#pragma unroll
  for (int j = 0; j < 8; ++j) {
    int idx = tid + (j << 8);
    int row = idx >> 4, ul = idx & 15;
    float4 gt = *(const float4*)&gtile[row][ul << 2];
    size_t cidx = (size_t)(bm + row) * Hn + u0 + ul;
    float si = 1.0f / (1.0f + expf(-gt.x));
    float sf = 1.0f / (1.0f + expf(-gt.y));
    float tg = tanhf(gt.z);
    float so = 1.0f / (1.0f + expf(-gt.w));
    float cn = sf * c[cidx] + si * tg;
    c[cidx] = cn;
    float hv = so * tanhf(cn);
    split16(hv, hoh[cidx], hol[cidx]);
  }
}

__global__ void __launch_bounds__(256) k_gates_fb(
    const _Float16* __restrict__ xh, const _Float16* __restrict__ xl,
    const _Float16* __restrict__ hih, const _Float16* __restrict__ hil,
    const _Float16* __restrict__ wph, const _Float16* __restrict__ wpl,
    const _Float16* __restrict__ vph, const _Float16* __restrict__ vpl,
    const float* __restrict__ biasp, float* __restrict__ c,
    _Float16* __restrict__ hoh, _Float16* __restrict__ hol) {
  __shared__ __align__(16) char smem[49152];
  int tid = threadIdx.x;
  f32x4 acch[4][2] = {};
  f32x4 accc[4][2] = {};
  int x8 = blockIdx.x & 7, q = blockIdx.x >> 3;
  int bn = (((q & 3) << 3) | x8) << 6;
  int bm = (q >> 2) << 7;
  int lane = tid & 63, wv = tid >> 6;
  int wr = (wv >> 1) << 6, wc = (wv & 1) << 5;
  int fr = lane & 15, c0 = lane >> 4;
  int rsub = lane >> 2, cp = lane & 3;
  int psw = (c0 ^ ((fr >> 1) & 3)) << 3;
  auto stage = [&](int p, int t) {
    const _Float16* As_h = (t < 16) ? xh : hih;
    const _Float16* As_l = (t < 16) ? xl : hil;
    const _Float16* Bs_h = (t < 16) ? wph : vph;
    const _Float16* Bs_l = (t < 16) ? wpl : vpl;
    int k0 = (t & 15) << 5;
    char* base = smem + p * 24576;
#pragma unroll
    for (int s = 0; s < 2; ++s) {
      int row = (((wv << 1) + s) << 4) + rsub;
      int koff = (cp ^ ((row >> 1) & 3)) << 3;
      size_t ga = (size_t)(bm + row) * 512 + k0 + koff;
      int lo = (row << 5) + (cp << 3);
      gload16((_Float16*)base + lo, As_h + ga);
      gload16((_Float16*)(base + 8192) + lo, As_l + ga);
    }
    {
      int row = (wv << 4) + rsub;
      int koff = (cp ^ ((row >> 1) & 3)) << 3;
      size_t gb = (size_t)(bn + row) * 512 + k0 + koff;
      int lo = (row << 5) + (cp << 3);
      gload16((_Float16*)(base + 16384) + lo, Bs_h + gb);
      gload16((_Float16*)(base + 20480) + lo, Bs_l + gb);
    }
  };
  auto compute = [&](int p) {
    char* base = smem + p * 24576;
    _Float16 (*Ah)[32] = (_Float16(*)[32])base;
    _Float16 (*Al)[32] = (_Float16(*)[32])(base + 8192);
    _Float16 (*Bh)[32] = (_Float16(*)[32])(base + 16384);
    _Float16 (*Bl)[32] = (_Float16(*)[32])(base + 20480);
    half8 ah[4], al[4], bh[2], bl[2];
#pragma unroll
    for (int i = 0; i < 4; ++i) {
      int ra = wr + i * 16 + fr;
      ah[i] = *(const half8*)&Ah[ra][psw];
      al[i] = *(const half8*)&Al[ra][psw];
    }
#pragma unroll
    for (int i = 0; i < 2; ++i) {
      int rb = wc + i * 16 + fr;
      bh[i] = *(const half8*)&Bh[rb][psw];
      bl[i] = *(const half8*)&Bl[rb][psw];
    }
#pragma unroll
    for (int mi = 0; mi < 4; ++mi)
#pragma unroll
      for (int ni = 0; ni < 2; ++ni) {
        acch[mi][ni] = __builtin_amdgcn_mfma_f32_16x16x32_f16(ah[mi], bh[ni], acch[mi][ni], 0, 0, 0);
        accc[mi][ni] = __builtin_amdgcn_mfma_f32_16x16x32_f16(ah[mi], bl[ni], accc[mi][ni], 0, 0, 0);
        accc[mi][ni] = __builtin_amdgcn_mfma_f32_16x16x32_f16(al[mi], bh[ni], accc[mi][ni], 0, 0, 0);
      }
  };
  stage(0, 0); stage(1, 1);
  asm volatile("s_waitcnt vmcnt(6)" ::: "memory");
  SCHEDB(); SBAR(); SCHEDB();
  int pc = 0, ps = 2;
  for (int t = 0; t < 32; ++t) {
    if (t + 2 < 32) stage(ps, t + 2);
    compute(pc);
    SCHEDB();
    if (t + 2 < 32) { asm volatile("s_waitcnt vmcnt(6) lgkmcnt(0)" ::: "memory"); }
    else            { asm volatile("s_waitcnt vmcnt(0) lgkmcnt(0)" ::: "memory"); }
    SCHEDB(); SBAR(); SCHEDB();
    pc = (pc == 2) ? 0 : pc + 1;
    ps = (ps == 2) ? 0 : ps + 1;
  }
  float (*gtile)[68] = (float(*)[68])smem;
  int orow = (lane >> 4) << 2, ocol = lane & 15;
#pragma unroll
  for (int mi = 0; mi < 4; ++mi)
#pragma unroll
    for (int ni = 0; ni < 2; ++ni) {
      int col = wc + ni * 16 + ocol;
      float bsum = biasp[bn + col];
#pragma unroll
      for (int r = 0; r < 4; ++r) {
        int row = wr + mi * 16 + orow + r;
        gtile[row][col] = acch[mi][ni][r] + accc[mi][ni][r] * (1.0f / 2048.0f) + bsum;
      }
    }
  __syncthreads();
  cell_update256(gtile, tid, bm, bn >> 2, c, hoh, hol);
}

__global__ void __launch_bounds__(256) k_logits_fb(
    const _Float16* __restrict__ hh, const _Float16* __restrict__ hl,
    const _Float16* __restrict__ outwh, const _Float16* __restrict__ outwl,
    const float* __restrict__ outb, float* __restrict__ logits) {
  __shared__ __align__(16) char smem[65536];
  int tid = threadIdx.x;
  f32x4 acch[4][4] = {};
  f32x4 accc[4][4] = {};
  int x8 = blockIdx.x & 7, q = blockIdx.x >> 3;          // grid 512
  int bn = (((q & 7) << 3) | x8) << 7;
  int bm = (q >> 3) << 7;
  int lane = tid & 63, wv = tid >> 6;
  int wr = (wv >> 1) << 6, wc = (wv & 1) << 6;
  int fr = lane & 15, c0 = lane >> 4;
  int rsub = lane >> 2, cp = lane & 3;
  int psw = (c0 ^ ((fr >> 1) & 3)) << 3;
  auto stage = [&](int p, int t) {
    int k0 = t << 5;
    char* base = smem + (p << 15);
#pragma unroll
    for (int s = 0; s < 2; ++s) {
      int row = (((wv << 1) + s) << 4) + rsub;
      int koff = (cp ^ ((row >> 1) & 3)) << 3;
      size_t ga = (size_t)(bm + row) * 512 + k0 + koff;
      size_t gb = (size_t)(bn + row) * 512 + k0 + koff;
      int lo = (row << 5) + (cp << 3);
      gload16((_Float16*)base + lo, hh + ga);
      gload16((_Float16*)(base + 8192) + lo, hl + ga);
      gload16((_Float16*)(base + 16384) + lo, outwh + gb);
      gload16((_Float16*)(base + 24576) + lo, outwl + gb);
    }
  };
  auto compute = [&](int p) {
    char* base = smem + (p << 15);
    _Float16 (*Ah)[32] = (_Float16(*)[32])base;
    _Float16 (*Al)[32] = (_Float16(*)[32])(base + 8192);
    _Float16 (*Bh)[32] = (_Float16(*)[32])(base + 16384);
    _Float16 (*Bl)[32] = (_Float16(*)[32])(base + 24576);
    half8 ah[4], al[4], bh[4], bl[4];
#pragma unroll
    for (int i = 0; i < 4; ++i) {
      int ra = wr + i * 16 + fr;
      int rb = wc + i * 16 + fr;
      ah[i] = *(const half8*)&Ah[ra][psw];
      al[i] = *(const half8*)&Al[ra][psw];
      bh[i] = *(const half8*)&Bh[rb][psw];
      bl[i] = *(const half8*)&Bl[rb][psw];
    }
#pragma unroll
    for (int mi = 0; mi < 4; ++mi)
#pragma unroll
      for (int ni = 0; ni < 4; ++ni) {
        acch[mi][ni] = __builtin_amdgcn_mfma_f32_16x16x32_f16(ah[mi], bh[ni], acch[mi][ni], 0, 0, 0);
        accc[mi][ni] = __builtin_amdgcn_mfma_f32_16x16x32_f16(ah[mi], bl[ni], accc[mi][ni], 0, 0, 0);
        accc[mi][ni] = __builtin_amdgcn_mfma_f32_16x16x32_f16(al[mi], bh[ni], accc[mi][ni], 0, 0, 0);
      }
  };
  stage(0, 0);
  __syncthreads();
  int cur = 0;
  for (int t = 0; t < 16; ++t) {
    if (t + 1 < 16) stage(cur ^ 1, t + 1);
    compute(cur);
    __syncthreads();
    cur ^= 1;
  }
  int orow = (lane >> 4) << 2, ocol = lane & 15;
#pragma unroll
  for (int mi = 0; mi < 4; ++mi)
#pragma unroll
    for (int ni = 0; ni < 4; ++ni) {
      int colg = bn + wc + ni * 16 + ocol;
      float bv = outb[colg];
#pragma unroll
      for (int r = 0; r < 4; ++r) {
        int rowg = bm + wr + mi * 16 + orow + r;
        logits[(size_t)rowg * Vn + colg] =
            acch[mi][ni][r] + accc[mi][ni][r] * (1.0f / 2048.0f) + bv;
      }
    }
}

// ---------------- f32 register-tiled GEMM (k_fc1 only, runs once) ----------
__device__ __forceinline__ void gemm_seg(
    const float* __restrict__ A, int lda, const float* __restrict__ W, int ldw,
    int bm, int bn, int tid, int tm8, int tn4,
    float (*As)[132], float (*Bs)[68], float acc[8][4]) {
  for (int k0 = 0; k0 < 512; k0 += 16) {
#pragma unroll
    for (int it = 0; it < 2; ++it) {
      int g = (it << 8) + tid;
      int m = g >> 2, kq = g & 3;
      const float4 v = *(const float4*)(A + (size_t)(bm + m) * lda + k0 + (kq << 2));
      As[(kq << 2) + 0][m] = v.x; As[(kq << 2) + 1][m] = v.y;
      As[(kq << 2) + 2][m] = v.z; As[(kq << 2) + 3][m] = v.w;
    }
    {
      int m = tid >> 2, kq = tid & 3;
      const float4 v = *(const float4*)(W + (size_t)(bn + m) * ldw + k0 + (kq << 2));
      Bs[(kq << 2) + 0][m] = v.x; Bs[(kq << 2) + 1][m] = v.y;
      Bs[(kq << 2) + 2][m] = v.z; Bs[(kq << 2) + 3][m] = v.w;
    }
    __syncthreads();
#pragma unroll
    for (int k = 0; k < 16; ++k) {
      const float4 a0 = *(const float4*)&As[k][tm8];
      const float4 a1 = *(const float4*)&As[k][tm8 + 4];
      const float4 bv = *(const float4*)&Bs[k][tn4];
      float av[8] = {a0.x, a0.y, a0.z, a0.w, a1.x, a1.y, a1.z, a1.w};
      float bw[4] = {bv.x, bv.y, bv.z, bv.w};
#pragma unroll
      for (int i = 0; i < 8; ++i)
#pragma unroll
        for (int j = 0; j < 4; ++j)
          acc[i][j] = fmaf(av[i], bw[j], acc[i][j]);
    }
    __syncthreads();
  }
}

// ---------------- init: h0 = relu(img@fc1^T + b) -> hh/hl; c=0; x=0 --------
__global__ void __launch_bounds__(256) k_fc1(
    const float* __restrict__ img, const float* __restrict__ fc1w,
    const float* __restrict__ fc1b,
    _Float16* __restrict__ hh, _Float16* __restrict__ hl,
    _Float16* __restrict__ xh, _Float16* __restrict__ xl,
    float* __restrict__ c) {
  __shared__ float As[16][132];
  __shared__ float Bs[16][68];
  int tid = threadIdx.x;
  int tm8 = (tid >> 4) << 3;
  int tn4 = (tid & 15) << 2;
  float acc[8][4] = {};
  int bm = (blockIdx.x >> 3) << 7;
  int bn = (blockIdx.x & 7) << 6;
  gemm_seg(img, Dn, fc1w, Dn, bm, bn, tid, tm8, tn4, As, Bs, acc);
  const float4 b4 = *(const float4*)(fc1b + bn + tn4);
  float bb[4] = {b4.x, b4.y, b4.z, b4.w};
#pragma unroll
  for (int i = 0; i < 8; ++i) {
    size_t off = (size_t)(bm + tm8 + i) * Hn + bn + tn4;
#pragma unroll
    for (int j = 0; j < 4; ++j) {
      float hv = fmaxf(acc[i][j] + bb[j], 0.f);
      split16(hv, hh[off + j], hl[off + j]);
      xh[off + j] = (_Float16)0.f;
      xl[off + j] = (_Float16)0.f;
      c[off + j] = 0.f;
    }
  }
}

// ---------------- fused softmax + gumbel-argmax + outputs + next-x ---------
// Partitionable threefry: bits(j) = y0 ^ y1, (y0,y1) = threefry(step_key, 0, j), j = b*V+v.
// Native __logf/__expf validated R11/R12 (identical sampling, absmax 1.9e-6).
// Entropy folded into pass 2: ent = lse - T/S, T = sum e^sh * sh.
__global__ void __launch_bounds__(256) k_sm(
    const float* __restrict__ logits, const float* __restrict__ emb,
    float* __restrict__ mask, float* __restrict__ out_base,
    _Float16* __restrict__ xh, _Float16* __restrict__ xl,
    unsigned k0, unsigned k1, int t) {
  __shared__ __align__(16) float row[Vn];
  __shared__ float rf[256];
  __shared__ int ri[256];
  __shared__ double rd[256];
  __shared__ double rt[256];
  int b = blockIdx.x, tid = threadIdx.x;
  const float4* src = (const float4*)(logits + (size_t)b * Vn);
  float4* dst = (float4*)row;
  for (int i = tid; i < Vn / 4; i += 256) dst[i] = src[i];
  __syncthreads();

  // pass 1: row max + gumbel argmax (first-index tiebreak)
  float m = -INFINITY, best = -INFINITY;
  int bidx = Vn;
  for (int v = tid; v < Vn; v += 256) {
    float lg = row[v];
    m = fmaxf(m, lg);
    unsigned j = (unsigned)(b * Vn + v);
    unsigned y0, y1;
    threefry2x32(k0, k1, 0u, j, y0, y1);
    unsigned bits = y0 ^ y1;
    float uf = fmaxf(__uint_as_float((bits >> 9) | 0x3F800000u) - 1.0f,
                     1.17549435e-38f);
    float g = -__logf(-__logf(uf));
    float val = lg + g;
    if (val > best) { best = val; bidx = v; }   // ascending v -> first max kept
  }
  rf[tid] = m;
  __syncthreads();
  for (int s = 128; s > 0; s >>= 1) {
    if (tid < s) rf[tid] = fmaxf(rf[tid], rf[tid + s]);
    __syncthreads();
  }
  float rowmax = rf[0];
  __syncthreads();
  rf[tid] = best; ri[tid] = bidx;
  __syncthreads();
  for (int s = 128; s > 0; s >>= 1) {
    if (tid < s) {
      float v2 = rf[tid + s]; int i2 = ri[tid + s];
      if (v2 > rf[tid] || (v2 == rf[tid] && i2 < ri[tid])) { rf[tid] = v2; ri[tid] = i2; }
    }
    __syncthreads();
  }
  int act = ri[0];

  // pass 2: S = sum e^sh, T = sum e^sh * sh (f64 adds)
  double sacc = 0.0, tacc = 0.0;
  for (int v = tid; v < Vn; v += 256) {
    float sh = row[v] - rowmax;
    float e = __expf(sh);
    sacc += (double)e;
    tacc += (double)(e * sh);
  }
  rd[tid] = sacc; rt[tid] = tacc;
  __syncthreads();
  for (int s = 128; s > 0; s >>= 1) {
    if (tid < s) { rd[tid] += rd[tid + s]; rt[tid] += rt[tid + s]; }
    __syncthreads();
  }
  double S = rd[0], T = rt[0];
  double lse = log(S);
  float mk = mask[b];

  // pass 3 (float4): probs + lps
  float* probs = out_base + 3 * Bn * Tn + ((size_t)(b * Tn + t)) * Vn;
  for (int v0 = tid << 2; v0 < Vn; v0 += 1024) {
    float4 l4 = *(const float4*)&row[v0];
    float lp[4];
    lp[0] = (float)((double)(l4.x - rowmax) - lse);
    lp[1] = (float)((double)(l4.y - rowmax) - lse);
    lp[2] = (float)((double)(l4.z - rowmax) - lse);
    lp[3] = (float)((double)(l4.w - rowmax) - lse);
    float4 o = {__expf(lp[0]) * mk, __expf(lp[1]) * mk,
                __expf(lp[2]) * mk, __expf(lp[3]) * mk};
    *(float4*)&probs[v0] = o;
    int d = act - v0;
    if (d >= 0 && d < 4)
      out_base[Bn * Tn + b * Tn + t] = lp[d] * mk;  // lps
  }
  // fused next-input: x = emb[act] (split), mask update (eos=0)
  for (int j = tid; j < Hn; j += 256) {
    float v = emb[(size_t)act * Hn + j];
    split16(v, xh[(size_t)b * Hn + j], xl[(size_t)b * Hn + j]);
  }
  if (tid == 0) {
    out_base[2 * Bn * Tn + b * Tn + t] = (float)(lse - T / S) * mk;  // ents
    out_base[b * Tn + t] = (float)act;                               // msgs
    mask[b] = mk * (act == 0 ? 0.f : 1.f);
  }
}

extern "C" void kernel_launch(void* const* d_in, const int* in_sizes, int n_in,
                              void* d_out, int out_size, void* d_ws, size_t ws_size,
                              hipStream_t stream) {
  const float* img  = (const float*)d_in[0];
  const float* emb  = (const float*)d_in[1];
  const float* fc1w = (const float*)d_in[2];
  const float* fc1b = (const float*)d_in[3];
  const float* wih  = (const float*)d_in[4];
  const float* whh  = (const float*)d_in[5];
  const float* bih  = (const float*)d_in[6];
  const float* bhh  = (const float*)d_in[7];
  const float* outw = (const float*)d_in[8];
  const float* outb = (const float*)d_in[9];
  float* out = (float*)d_out;

  float* ws = (float*)d_ws;
  float* c      = ws;                          // B*H
  float* mask   = c + Bn * Hn;                 // B
  float* biasp  = mask + Bn;                   // G4
  float* logits = biasp + G4;                  // B*V
  _Float16* wph  = (_Float16*)(logits + (size_t)Bn * Vn);  // permuted wih hi
  _Float16* wpl  = wph + (size_t)G4 * Hn;
  _Float16* vph  = wpl + (size_t)G4 * Hn;                  // permuted whh hi
  _Float16* vpl  = vph + (size_t)G4 * Hn;
  _Float16* outwh = vpl + (size_t)G4 * Hn;
  _Float16* outwl = outwh + (size_t)Vn * Hn;
  _Float16* xh = outwl + (size_t)Vn * Hn;
  _Float16* xl = xh + Bn * Hn;
  _Float16* hhA = xl + Bn * Hn;
  _Float16* hlA = hhA + Bn * Hn;
  _Float16* hhB = hlA + Bn * Hn;
  _Float16* hlB = hhB + Bn * Hn;

  // step keys: fold-like split (jax_threefry_partitionable):
  // keys[t] = threefry2x32(key=(0,42), x0=0, x1=t)
  unsigned kk0[Tn], kk1[Tn];
  for (int i = 0; i < Tn; ++i) {
    unsigned y0, y1;
    threefry2x32(0u, 42u, 0u, (unsigned)i, y0, y1);
    kk0[i] = y0; kk1[i] = y1;
  }

  // dynamic-LDS opt-in (>64KB). Non-stream calls; graph-capture safe. If the
  // stack rejects them, fall back to the proven static-LDS kernels.
  bool big_lds =
      (hipFuncSetAttribute((const void*)k_gates,
                           hipFuncAttributeMaxDynamicSharedMemorySize, 73728) == hipSuccess) &&
      (hipFuncSetAttribute((const void*)k_logits,
                           hipFuncAttributeMaxDynamicSharedMemorySize, 147456) == hipSuccess);

  // one-time preps
  k_prep_perm<<<(G4 * Hn) / 256, 256, 0, stream>>>(wih, wph, wpl);
  k_prep_perm<<<(G4 * Hn) / 256, 256, 0, stream>>>(whh, vph, vpl);
  k_prep<<<(Vn * Hn) / 256, 256, 0, stream>>>(outw, outwh, outwl, Vn * Hn);
  k_prep_bias<<<G4 / 256, 256, 0, stream>>>(bih, bhh, biasp);
  k_mask<<<4, 256, 0, stream>>>(mask);
  k_fc1<<<64, 256, 0, stream>>>(img, fc1w, fc1b, hhA, hlA, xh, xl, c);

  for (int t = 0; t < Tn; ++t) {
    const _Float16* hih = (t & 1) ? hhB : hhA;
    const _Float16* hil = (t & 1) ? hlB : hlA;
    _Float16* hoh = (t & 1) ? hhA : hhB;
    _Float16* hol = (t & 1) ? hlA : hlB;
    if (big_lds) {
      k_gates<<<256, 512, 73728, stream>>>(
          xh, xl, hih, hil, wph, wpl, vph, vpl, biasp, c, hoh, hol);
      k_logits<<<256, 512, 147456, stream>>>(
          hoh, hol, outwh, outwl, outb, logits);
    } else {
      k_gates_fb<<<256, 256, 0, stream>>>(
          xh, xl, hih, hil, wph, wpl, vph, vpl, biasp, c, hoh, hol);
      k_logits_fb<<<512, 256, 0, stream>>>(
          hoh, hol, outwh, outwl, outb, logits);
    }
    k_sm<<<Bn, 256, 0, stream>>>(logits, emb, mask, out, xh, xl, kk0[t], kk1[t], t);
  }
}

// Round 15
// 1899.268 us; speedup vs baseline: 1.0716x; 1.0295x over previous
//
#include <hip/hip_runtime.h>
#include <math.h>

#define Bn 1024
#define Dn 512
#define Hn 512
#define Vn 8192
#define Tn 20
#define G4 2048

typedef _Float16 half8 __attribute__((ext_vector_type(8)));
typedef float f32x4 __attribute__((ext_vector_type(4)));

#define SCHEDB() __builtin_amdgcn_sched_barrier(0)
#define SBAR()   __builtin_amdgcn_s_barrier()

// ---------------- threefry2x32 (JAX-exact, 20 rounds) ----------------
__host__ __device__ __forceinline__ void threefry2x32(
    unsigned k0, unsigned k1, unsigned x0, unsigned x1,
    unsigned& y0, unsigned& y1) {
  unsigned ks2 = k0 ^ k1 ^ 0x1BD11BDAu;
#define TF_RND(r) { x0 += x1; x1 = (x1 << (r)) | (x1 >> (32 - (r))); x1 ^= x0; }
  x0 += k0; x1 += k1;
  TF_RND(13) TF_RND(15) TF_RND(26) TF_RND(6)
  x0 += k1; x1 += ks2 + 1u;
  TF_RND(17) TF_RND(29) TF_RND(16) TF_RND(24)
  x0 += ks2; x1 += k0 + 2u;
  TF_RND(13) TF_RND(15) TF_RND(26) TF_RND(6)
  x0 += k0; x1 += k1 + 3u;
  TF_RND(17) TF_RND(29) TF_RND(16) TF_RND(24)
  x0 += k1; x1 += ks2 + 4u;
  TF_RND(13) TF_RND(15) TF_RND(26) TF_RND(6)
  x0 += ks2; x1 += k0 + 5u;
#undef TF_RND
  y0 = x0; y1 = x1;
}

// f32 -> f16 hi/lo split. lo scaled by 2^11 to stay in f16 normal range.
__device__ __forceinline__ void split16(float v, _Float16& hi, _Float16& lo) {
  float h = (fabsf(v) < 6.2e-5f) ? 0.f : (float)(_Float16)v;  // keep hi out of f16-denorm
  hi = (_Float16)h;
  lo = (_Float16)((v - h) * 2048.0f);
}

// async 16B global->LDS. HW dest = wave-uniform base + lane*16; our per-lane
// addressing (row=f(lane>>2), chunk=lane&3) equals exactly that mapping.
__device__ __forceinline__ void gload16(void* l, const void* g) {
  __builtin_amdgcn_global_load_lds(
      (const __attribute__((address_space(1))) unsigned int*)g,
      (__attribute__((address_space(3))) unsigned int*)l, 16, 0, 0);
}

// ---------------- prep kernels (run every call; idempotent) ----------------
__global__ void k_prep(const float* __restrict__ w, _Float16* __restrict__ hi,
                       _Float16* __restrict__ lo, int n) {
  int i = blockIdx.x * blockDim.x + threadIdx.x;
  if (i >= n) return;
  split16(w[i], hi[i], lo[i]);
}

// gate-interleaved permutation: dst row u*4+g  <-  src row g*512+u
__global__ void k_prep_perm(const float* __restrict__ w, _Float16* __restrict__ hi,
                            _Float16* __restrict__ lo) {
  int i = blockIdx.x * blockDim.x + threadIdx.x;  // G4*Hn
  int rp = i >> 9, k = i & 511;
  int u = rp >> 2, g = rp & 3;
  split16(w[(size_t)((g << 9) + u) * 512 + k], hi[i], lo[i]);
}

__global__ void k_prep_bias(const float* __restrict__ bih, const float* __restrict__ bhh,
                            float* __restrict__ bp) {
  int i = blockIdx.x * blockDim.x + threadIdx.x;  // G4
  if (i >= G4) return;
  int u = i >> 2, g = i & 3;
  bp[i] = bih[(g << 9) + u] + bhh[(g << 9) + u];
}

__global__ void k_mask(float* __restrict__ mask) {
  int i = blockIdx.x * blockDim.x + threadIdx.x;
  if (i < Bn) mask[i] = 1.f;
}

// ================== gates GEMM: 8-wave 128x64, BK=64, 3-buf counted vmcnt(6) ==========
// Each 48 KB buffer holds TWO 32-wide K-sub-tiles -> 16 iterations, one barrier per 64-K.
// MFMA order per accumulator unchanged vs BK=32 version -> bit-identical output.
__global__ void __launch_bounds__(512) k_gates(
    const _Float16* __restrict__ xh, const _Float16* __restrict__ xl,
    const _Float16* __restrict__ hih, const _Float16* __restrict__ hil,
    const _Float16* __restrict__ wph, const _Float16* __restrict__ wpl,
    const _Float16* __restrict__ vph, const _Float16* __restrict__ vpl,
    const float* __restrict__ biasp, float* __restrict__ c,
    _Float16* __restrict__ hoh, _Float16* __restrict__ hol) {
  extern __shared__ __align__(16) char smem[];
  int tid = threadIdx.x;
  f32x4 acch[4] = {};
  f32x4 accc[4] = {};
  int x8 = blockIdx.x & 7, q = blockIdx.x >> 3;          // grid 256
  int bn = (((q & 3) << 3) | x8) << 6;
  int bm = (q >> 2) << 7;
  int lane = tid & 63, wv = tid >> 6;                    // 8 waves
  int wr = (wv >> 2) << 6, wc = (wv & 3) << 4;           // 2M x 4N
  int fr = lane & 15, c0 = lane >> 4;
  int rsub = lane >> 2, cp = lane & 3;
  int psw = (c0 ^ ((fr >> 1) & 3)) << 3;

  // stage one 32-wide sub-tile kk (0..31) into 24KB half `half_base`
  auto stage_sub = [&](char* half_base, int kk) {
    const _Float16* As_h = (kk < 16) ? xh : hih;
    const _Float16* As_l = (kk < 16) ? xl : hil;
    const _Float16* Bs_h = (kk < 16) ? wph : vph;
    const _Float16* Bs_l = (kk < 16) ? wpl : vpl;
    int k0 = (kk & 15) << 5;
    {
      int row = (wv << 4) + rsub;                        // 0..127
      int koff = (cp ^ ((row >> 1) & 3)) << 3;
      size_t ga = (size_t)(bm + row) * 512 + k0 + koff;
      int lo = (row << 5) + (cp << 3);
      gload16((_Float16*)half_base + lo, As_h + ga);
      gload16((_Float16*)(half_base + 8192) + lo, As_l + ga);
    }
    {
      int brow = ((wv & 3) << 4) + rsub;                 // 0..63
      int bkoff = (cp ^ ((brow >> 1) & 3)) << 3;
      size_t gb = (size_t)(bn + brow) * 512 + k0 + bkoff;
      int blo = (brow << 5) + (cp << 3);
      if (wv < 4) gload16((_Float16*)(half_base + 16384) + blo, Bs_h + gb);
      else        gload16((_Float16*)(half_base + 20480) + blo, Bs_l + gb);
    }
  };
  auto stage = [&](int p, int t) {                       // t = 0..15, covers kk=2t,2t+1
    char* base = smem + p * 49152;
    stage_sub(base, 2 * t);
    stage_sub(base + 24576, 2 * t + 1);
  };
  auto compute_sub = [&](char* half_base) {
    _Float16 (*Ah)[32] = (_Float16(*)[32])half_base;
    _Float16 (*Al)[32] = (_Float16(*)[32])(half_base + 8192);
    _Float16 (*Bh)[32] = (_Float16(*)[32])(half_base + 16384);
    _Float16 (*Bl)[32] = (_Float16(*)[32])(half_base + 20480);
    half8 ah[4], al[4];
#pragma unroll
    for (int i = 0; i < 4; ++i) {
      int ra = wr + i * 16 + fr;
      ah[i] = *(const half8*)&Ah[ra][psw];
      al[i] = *(const half8*)&Al[ra][psw];
    }
    half8 bh = *(const half8*)&Bh[wc + fr][psw];
    half8 bl = *(const half8*)&Bl[wc + fr][psw];
#pragma unroll
    for (int mi = 0; mi < 4; ++mi) {
      acch[mi] = __builtin_amdgcn_mfma_f32_16x16x32_f16(ah[mi], bh, acch[mi], 0, 0, 0);
      accc[mi] = __builtin_amdgcn_mfma_f32_16x16x32_f16(ah[mi], bl, accc[mi], 0, 0, 0);
      accc[mi] = __builtin_amdgcn_mfma_f32_16x16x32_f16(al[mi], bh, accc[mi], 0, 0, 0);
    }
  };
  auto compute = [&](int p) {
    char* base = smem + p * 49152;
    compute_sub(base);
    compute_sub(base + 24576);
  };

  stage(0, 0); stage(1, 1);
  asm volatile("s_waitcnt vmcnt(6)" ::: "memory");       // drain buf0's 6, keep buf1's 6
  SCHEDB(); SBAR(); SCHEDB();
  int pc = 0, ps = 2;
  for (int t = 0; t < 16; ++t) {
    if (t + 2 < 16) stage(ps, t + 2);
    compute(pc);
    SCHEDB();
    if (t + 2 < 16) { asm volatile("s_waitcnt vmcnt(6) lgkmcnt(0)" ::: "memory"); }
    else            { asm volatile("s_waitcnt vmcnt(0) lgkmcnt(0)" ::: "memory"); }
    SCHEDB(); SBAR(); SCHEDB();
    pc = (pc == 2) ? 0 : pc + 1;
    ps = (ps == 2) ? 0 : ps + 1;
  }

  float (*gtile)[68] = (float(*)[68])smem;
  int orow = (lane >> 4) << 2, ocol = lane & 15;
  {
    int col = wc + ocol;
    float bsum = biasp[bn + col];
#pragma unroll
    for (int mi = 0; mi < 4; ++mi)
#pragma unroll
      for (int r = 0; r < 4; ++r) {
        int row = wr + mi * 16 + orow + r;
        gtile[row][col] = acch[mi][r] + accc[mi][r] * (1.0f / 2048.0f) + bsum;
      }
  }
  __syncthreads();
  // fused cell update, 512 threads: 2048 gate-quads, 4 per thread
  int u0 = bn >> 2;
#pragma unroll
  for (int j = 0; j < 4; ++j) {
    int idx = tid + (j << 9);
    int row = idx >> 4, ul = idx & 15;
    float4 gt = *(const float4*)&gtile[row][ul << 2];  // i,f,g,o
    size_t cidx = (size_t)(bm + row) * Hn + u0 + ul;
    float si = 1.0f / (1.0f + expf(-gt.x));
    float sf = 1.0f / (1.0f + expf(-gt.y));
    float tg = tanhf(gt.z);
    float so = 1.0f / (1.0f + expf(-gt.w));
    float cn = sf * c[cidx] + si * tg;
    c[cidx] = cn;
    float hv = so * tanhf(cn);
    split16(hv, hoh[cidx], hol[cidx]);
  }
}

// ================== logits GEMM: 256x128 tile, 512 thr, 3-buf counted ==================
__global__ void __launch_bounds__(512) k_logits(
    const _Float16* __restrict__ hh, const _Float16* __restrict__ hl,
    const _Float16* __restrict__ outwh, const _Float16* __restrict__ outwl,
    const float* __restrict__ outb, float* __restrict__ logits) {
  extern __shared__ __align__(16) char smem[];
  int tid = threadIdx.x;
  f32x4 acch[4][4] = {};
  f32x4 accc[4][4] = {};
  int x8 = blockIdx.x & 7, q = blockIdx.x >> 3;          // grid 256
  int bn = (((q & 7) << 3) | x8) << 7;                   // 64 n-blocks of 128
  int bm = (q >> 3) << 8;                                // 4 m-blocks of 256
  int lane = tid & 63, wv = tid >> 6;                    // 8 waves
  int wr = (wv >> 1) << 6, wc = (wv & 1) << 6;
  int fr = lane & 15, c0 = lane >> 4;
  int rsub = lane >> 2, cp = lane & 3;
  int psw = (c0 ^ ((fr >> 1) & 3)) << 3;

  auto stage = [&](int p, int t) {
    int k0 = t << 5;
    char* base = smem + p * 49152;
#pragma unroll
    for (int s = 0; s < 2; ++s) {
      int row = (((wv << 1) + s) << 4) + rsub;           // 0..255
      int koff = (cp ^ ((row >> 1) & 3)) << 3;
      size_t ga = (size_t)(bm + row) * 512 + k0 + koff;
      int lo = (row << 5) + (cp << 3);
      gload16((_Float16*)base + lo, hh + ga);
      gload16((_Float16*)(base + 16384) + lo, hl + ga);
    }
    {
      int row = tid >> 2;                                 // 0..127
      int koff = (cp ^ ((row >> 1) & 3)) << 3;
      size_t gb = (size_t)(bn + row) * 512 + k0 + koff;
      int lo = (row << 5) + (cp << 3);
      gload16((_Float16*)(base + 32768) + lo, outwh + gb);
      gload16((_Float16*)(base + 40960) + lo, outwl + gb);
    }
  };
  auto compute = [&](int p) {
    char* base = smem + p * 49152;
    _Float16 (*Ah)[32] = (_Float16(*)[32])base;
    _Float16 (*Al)[32] = (_Float16(*)[32])(base + 16384);
    _Float16 (*Bh)[32] = (_Float16(*)[32])(base + 32768);
    _Float16 (*Bl)[32] = (_Float16(*)[32])(base + 40960);
    half8 ah[4], al[4], bh[4], bl[4];
#pragma unroll
    for (int i = 0; i < 4; ++i) {
      int ra = wr + i * 16 + fr;
      int rb = wc + i * 16 + fr;
      ah[i] = *(const half8*)&Ah[ra][psw];
      al[i] = *(const half8*)&Al[ra][psw];
      bh[i] = *(const half8*)&Bh[rb][psw];
      bl[i] = *(const half8*)&Bl[rb][psw];
    }
#pragma unroll
    for (int mi = 0; mi < 4; ++mi)
#pragma unroll
      for (int ni = 0; ni < 4; ++ni) {
        acch[mi][ni] = __builtin_amdgcn_mfma_f32_16x16x32_f16(ah[mi], bh[ni], acch[mi][ni], 0, 0, 0);
        accc[mi][ni] = __builtin_amdgcn_mfma_f32_16x16x32_f16(ah[mi], bl[ni], accc[mi][ni], 0, 0, 0);
        accc[mi][ni] = __builtin_amdgcn_mfma_f32_16x16x32_f16(al[mi], bh[ni], accc[mi][ni], 0, 0, 0);
      }
  };

  stage(0, 0); stage(1, 1);
  asm volatile("s_waitcnt vmcnt(6)" ::: "memory");
  SCHEDB(); SBAR(); SCHEDB();
  int pc = 0, ps = 2;
  for (int t = 0; t < 16; ++t) {
    if (t + 2 < 16) stage(ps, t + 2);
    compute(pc);
    SCHEDB();
    if (t + 2 < 16) { asm volatile("s_waitcnt vmcnt(6) lgkmcnt(0)" ::: "memory"); }
    else            { asm volatile("s_waitcnt vmcnt(0) lgkmcnt(0)" ::: "memory"); }
    SCHEDB(); SBAR(); SCHEDB();
    pc = (pc == 2) ? 0 : pc + 1;
    ps = (ps == 2) ? 0 : ps + 1;
  }

  int orow = (lane >> 4) << 2, ocol = lane & 15;
#pragma unroll
  for (int mi = 0; mi < 4; ++mi)
#pragma unroll
    for (int ni = 0; ni < 4; ++ni) {
      int colg = bn + wc + ni * 16 + ocol;
      float bv = outb[colg];
#pragma unroll
      for (int r = 0; r < 4; ++r) {
        int rowg = bm + wr + mi * 16 + orow + r;
        logits[(size_t)rowg * Vn + colg] =
            acch[mi][ni][r] + accc[mi][ni][r] * (1.0f / 2048.0f) + bv;
      }
    }
}

// ================== FALLBACK kernels (R8-proven, static <=64KB LDS) ==================
__device__ __forceinline__ void cell_update256(
    float (*gtile)[68], int tid, int bm, int u0, float* __restrict__ c,
    _Float16* __restrict__ hoh, _Float16* __restrict__ hol) {
#pragma unroll
  for (int j = 0; j < 8; ++j) {
    int idx = tid + (j << 8);
    int row = idx >> 4, ul = idx & 15;
    float4 gt = *(const float4*)&gtile[row][ul << 2];
    size_t cidx = (size_t)(bm + row) * Hn + u0 + ul;
    float si = 1.0f / (1.0f + expf(-gt.x));
    float sf = 1.0f / (1.0f + expf(-gt.y));
    float tg = tanhf(gt.z);
    float so = 1.0f / (1.0f + expf(-gt.w));
    float cn = sf * c[cidx] + si * tg;
    c[cidx] = cn;
    float hv = so * tanhf(cn);
    split16(hv, hoh[cidx], hol[cidx]);
  }
}

__global__ void __launch_bounds__(256) k_gates_fb(
    const _Float16* __restrict__ xh, const _Float16* __restrict__ xl,
    const _Float16* __restrict__ hih, const _Float16* __restrict__ hil,
    const _Float16* __restrict__ wph, const _Float16* __restrict__ wpl,
    const _Float16* __restrict__ vph, const _Float16* __restrict__ vpl,
    const float* __restrict__ biasp, float* __restrict__ c,
    _Float16* __restrict__ hoh, _Float16* __restrict__ hol) {
  __shared__ __align__(16) char smem[49152];
  int tid = threadIdx.x;
  f32x4 acch[4][2] = {};
  f32x4 accc[4][2] = {};
  int x8 = blockIdx.x & 7, q = blockIdx.x >> 3;
  int bn = (((q & 3) << 3) | x8) << 6;
  int bm = (q >> 2) << 7;
  int lane = tid & 63, wv = tid >> 6;
  int wr = (wv >> 1) << 6, wc = (wv & 1) << 5;
  int fr = lane & 15, c0 = lane >> 4;
  int rsub = lane >> 2, cp = lane & 3;
  int psw = (c0 ^ ((fr >> 1) & 3)) << 3;
  auto stage = [&](int p, int t) {
    const _Float16* As_h = (t < 16) ? xh : hih;
    const _Float16* As_l = (t < 16) ? xl : hil;
    const _Float16* Bs_h = (t < 16) ? wph : vph;
    const _Float16* Bs_l = (t < 16) ? wpl : vpl;
    int k0 = (t & 15) << 5;
    char* base = smem + p * 24576;
#pragma unroll
    for (int s = 0; s < 2; ++s) {
      int row = (((wv << 1) + s) << 4) + rsub;
      int koff = (cp ^ ((row >> 1) & 3)) << 3;
      size_t ga = (size_t)(bm + row) * 512 + k0 + koff;
      int lo = (row << 5) + (cp << 3);
      gload16((_Float16*)base + lo, As_h + ga);
      gload16((_Float16*)(base + 8192) + lo, As_l + ga);
    }
    {
      int row = (wv << 4) + rsub;
      int koff = (cp ^ ((row >> 1) & 3)) << 3;
      size_t gb = (size_t)(bn + row) * 512 + k0 + koff;
      int lo = (row << 5) + (cp << 3);
      gload16((_Float16*)(base + 16384) + lo, Bs_h + gb);
      gload16((_Float16*)(base + 20480) + lo, Bs_l + gb);
    }
  };
  auto compute = [&](int p) {
    char* base = smem + p * 24576;
    _Float16 (*Ah)[32] = (_Float16(*)[32])base;
    _Float16 (*Al)[32] = (_Float16(*)[32])(base + 8192);
    _Float16 (*Bh)[32] = (_Float16(*)[32])(base + 16384);
    _Float16 (*Bl)[32] = (_Float16(*)[32])(base + 20480);
    half8 ah[4], al[4], bh[2], bl[2];
#pragma unroll
    for (int i = 0; i < 4; ++i) {
      int ra = wr + i * 16 + fr;
      ah[i] = *(const half8*)&Ah[ra][psw];
      al[i] = *(const half8*)&Al[ra][psw];
    }
#pragma unroll
    for (int i = 0; i < 2; ++i) {
      int rb = wc + i * 16 + fr;
      bh[i] = *(const half8*)&Bh[rb][psw];
      bl[i] = *(const half8*)&Bl[rb][psw];
    }
#pragma unroll
    for (int mi = 0; mi < 4; ++mi)
#pragma unroll
      for (int ni = 0; ni < 2; ++ni) {
        acch[mi][ni] = __builtin_amdgcn_mfma_f32_16x16x32_f16(ah[mi], bh[ni], acch[mi][ni], 0, 0, 0);
        accc[mi][ni] = __builtin_amdgcn_mfma_f32_16x16x32_f16(ah[mi], bl[ni], accc[mi][ni], 0, 0, 0);
        accc[mi][ni] = __builtin_amdgcn_mfma_f32_16x16x32_f16(al[mi], bh[ni], accc[mi][ni], 0, 0, 0);
      }
  };
  stage(0, 0); stage(1, 1);
  asm volatile("s_waitcnt vmcnt(6)" ::: "memory");
  SCHEDB(); SBAR(); SCHEDB();
  int pc = 0, ps = 2;
  for (int t = 0; t < 32; ++t) {
    if (t + 2 < 32) stage(ps, t + 2);
    compute(pc);
    SCHEDB();
    if (t + 2 < 32) { asm volatile("s_waitcnt vmcnt(6) lgkmcnt(0)" ::: "memory"); }
    else            { asm volatile("s_waitcnt vmcnt(0) lgkmcnt(0)" ::: "memory"); }
    SCHEDB(); SBAR(); SCHEDB();
    pc = (pc == 2) ? 0 : pc + 1;
    ps = (ps == 2) ? 0 : ps + 1;
  }
  float (*gtile)[68] = (float(*)[68])smem;
  int orow = (lane >> 4) << 2, ocol = lane & 15;
#pragma unroll
  for (int mi = 0; mi < 4; ++mi)
#pragma unroll
    for (int ni = 0; ni < 2; ++ni) {
      int col = wc + ni * 16 + ocol;
      float bsum = biasp[bn + col];
#pragma unroll
      for (int r = 0; r < 4; ++r) {
        int row = wr + mi * 16 + orow + r;
        gtile[row][col] = acch[mi][ni][r] + accc[mi][ni][r] * (1.0f / 2048.0f) + bsum;
      }
    }
  __syncthreads();
  cell_update256(gtile, tid, bm, bn >> 2, c, hoh, hol);
}

__global__ void __launch_bounds__(256) k_logits_fb(
    const _Float16* __restrict__ hh, const _Float16* __restrict__ hl,
    const _Float16* __restrict__ outwh, const _Float16* __restrict__ outwl,
    const float* __restrict__ outb, float* __restrict__ logits) {
  __shared__ __align__(16) char smem[65536];
  int tid = threadIdx.x;
  f32x4 acch[4][4] = {};
  f32x4 accc[4][4] = {};
  int x8 = blockIdx.x & 7, q = blockIdx.x >> 3;          // grid 512
  int bn = (((q & 7) << 3) | x8) << 7;
  int bm = (q >> 3) << 7;
  int lane = tid & 63, wv = tid >> 6;
  int wr = (wv >> 1) << 6, wc = (wv & 1) << 6;
  int fr = lane & 15, c0 = lane >> 4;
  int rsub = lane >> 2, cp = lane & 3;
  int psw = (c0 ^ ((fr >> 1) & 3)) << 3;
  auto stage = [&](int p, int t) {
    int k0 = t << 5;
    char* base = smem + (p << 15);
#pragma unroll
    for (int s = 0; s < 2; ++s) {
      int row = (((wv << 1) + s) << 4) + rsub;
      int koff = (cp ^ ((row >> 1) & 3)) << 3;
      size_t ga = (size_t)(bm + row) * 512 + k0 + koff;
      size_t gb = (size_t)(bn + row) * 512 + k0 + koff;
      int lo = (row << 5) + (cp << 3);
      gload16((_Float16*)base + lo, hh + ga);
      gload16((_Float16*)(base + 8192) + lo, hl + ga);
      gload16((_Float16*)(base + 16384) + lo, outwh + gb);
      gload16((_Float16*)(base + 24576) + lo, outwl + gb);
    }
  };
  auto compute = [&](int p) {
    char* base = smem + (p << 15);
    _Float16 (*Ah)[32] = (_Float16(*)[32])base;
    _Float16 (*Al)[32] = (_Float16(*)[32])(base + 8192);
    _Float16 (*Bh)[32] = (_Float16(*)[32])(base + 16384);
    _Float16 (*Bl)[32] = (_Float16(*)[32])(base + 24576);
    half8 ah[4], al[4], bh[4], bl[4];
#pragma unroll
    for (int i = 0; i < 4; ++i) {
      int ra = wr + i * 16 + fr;
      int rb = wc + i * 16 + fr;
      ah[i] = *(const half8*)&Ah[ra][psw];
      al[i] = *(const half8*)&Al[ra][psw];
      bh[i] = *(const half8*)&Bh[rb][psw];
      bl[i] = *(const half8*)&Bl[rb][psw];
    }
#pragma unroll
    for (int mi = 0; mi < 4; ++mi)
#pragma unroll
      for (int ni = 0; ni < 4; ++ni) {
        acch[mi][ni] = __builtin_amdgcn_mfma_f32_16x16x32_f16(ah[mi], bh[ni], acch[mi][ni], 0, 0, 0);
        accc[mi][ni] = __builtin_amdgcn_mfma_f32_16x16x32_f16(ah[mi], bl[ni], accc[mi][ni], 0, 0, 0);
        accc[mi][ni] = __builtin_amdgcn_mfma_f32_16x16x32_f16(al[mi], bh[ni], accc[mi][ni], 0, 0, 0);
      }
  };
  stage(0, 0);
  __syncthreads();
  int cur = 0;
  for (int t = 0; t < 16; ++t) {
    if (t + 1 < 16) stage(cur ^ 1, t + 1);
    compute(cur);
    __syncthreads();
    cur ^= 1;
  }
  int orow = (lane >> 4) << 2, ocol = lane & 15;
#pragma unroll
  for (int mi = 0; mi < 4; ++mi)
#pragma unroll
    for (int ni = 0; ni < 4; ++ni) {
      int colg = bn + wc + ni * 16 + ocol;
      float bv = outb[colg];
#pragma unroll
      for (int r = 0; r < 4; ++r) {
        int rowg = bm + wr + mi * 16 + orow + r;
        logits[(size_t)rowg * Vn + colg] =
            acch[mi][ni][r] + accc[mi][ni][r] * (1.0f / 2048.0f) + bv;
      }
    }
}

// ---------------- f32 register-tiled GEMM (k_fc1 only, runs once) ----------
__device__ __forceinline__ void gemm_seg(
    const float* __restrict__ A, int lda, const float* __restrict__ W, int ldw,
    int bm, int bn, int tid, int tm8, int tn4,
    float (*As)[132], float (*Bs)[68], float acc[8][4]) {
  for (int k0 = 0; k0 < 512; k0 += 16) {
#pragma unroll
    for (int it = 0; it < 2; ++it) {
      int g = (it << 8) + tid;
      int m = g >> 2, kq = g & 3;
      const float4 v = *(const float4*)(A + (size_t)(bm + m) * lda + k0 + (kq << 2));
      As[(kq << 2) + 0][m] = v.x; As[(kq << 2) + 1][m] = v.y;
      As[(kq << 2) + 2][m] = v.z; As[(kq << 2) + 3][m] = v.w;
    }
    {
      int m = tid >> 2, kq = tid & 3;
      const float4 v = *(const float4*)(W + (size_t)(bn + m) * ldw + k0 + (kq << 2));
      Bs[(kq << 2) + 0][m] = v.x; Bs[(kq << 2) + 1][m] = v.y;
      Bs[(kq << 2) + 2][m] = v.z; Bs[(kq << 2) + 3][m] = v.w;
    }
    __syncthreads();
#pragma unroll
    for (int k = 0; k < 16; ++k) {
      const float4 a0 = *(const float4*)&As[k][tm8];
      const float4 a1 = *(const float4*)&As[k][tm8 + 4];
      const float4 bv = *(const float4*)&Bs[k][tn4];
      float av[8] = {a0.x, a0.y, a0.z, a0.w, a1.x, a1.y, a1.z, a1.w};
      float bw[4] = {bv.x, bv.y, bv.z, bv.w};
#pragma unroll
      for (int i = 0; i < 8; ++i)
#pragma unroll
        for (int j = 0; j < 4; ++j)
          acc[i][j] = fmaf(av[i], bw[j], acc[i][j]);
    }
    __syncthreads();
  }
}

// ---------------- init: h0 = relu(img@fc1^T + b) -> hh/hl; c=0; x=0 --------
__global__ void __launch_bounds__(256) k_fc1(
    const float* __restrict__ img, const float* __restrict__ fc1w,
    const float* __restrict__ fc1b,
    _Float16* __restrict__ hh, _Float16* __restrict__ hl,
    _Float16* __restrict__ xh, _Float16* __restrict__ xl,
    float* __restrict__ c) {
  __shared__ float As[16][132];
  __shared__ float Bs[16][68];
  int tid = threadIdx.x;
  int tm8 = (tid >> 4) << 3;
  int tn4 = (tid & 15) << 2;
  float acc[8][4] = {};
  int bm = (blockIdx.x >> 3) << 7;
  int bn = (blockIdx.x & 7) << 6;
  gemm_seg(img, Dn, fc1w, Dn, bm, bn, tid, tm8, tn4, As, Bs, acc);
  const float4 b4 = *(const float4*)(fc1b + bn + tn4);
  float bb[4] = {b4.x, b4.y, b4.z, b4.w};
#pragma unroll
  for (int i = 0; i < 8; ++i) {
    size_t off = (size_t)(bm + tm8 + i) * Hn + bn + tn4;
#pragma unroll
    for (int j = 0; j < 4; ++j) {
      float hv = fmaxf(acc[i][j] + bb[j], 0.f);
      split16(hv, hh[off + j], hl[off + j]);
      xh[off + j] = (_Float16)0.f;
      xl[off + j] = (_Float16)0.f;
      c[off + j] = 0.f;
    }
  }
}

// ---------------- fused softmax + gumbel-argmax + outputs + next-x ---------
// Partitionable threefry: bits(j) = y0 ^ y1, (y0,y1) = threefry(step_key, 0, j), j = b*V+v.
// Native __logf/__expf validated R11/R12 (identical sampling, absmax 1.9e-6).
// Entropy folded into pass 2: ent = lse - T/S, T = sum e^sh * sh.
__global__ void __launch_bounds__(256) k_sm(
    const float* __restrict__ logits, const float* __restrict__ emb,
    float* __restrict__ mask, float* __restrict__ out_base,
    _Float16* __restrict__ xh, _Float16* __restrict__ xl,
    unsigned k0, unsigned k1, int t) {
  __shared__ __align__(16) float row[Vn];
  __shared__ float rf[256];
  __shared__ int ri[256];
  __shared__ double rd[256];
  __shared__ double rt[256];
  int b = blockIdx.x, tid = threadIdx.x;
  const float4* src = (const float4*)(logits + (size_t)b * Vn);
  float4* dst = (float4*)row;
  for (int i = tid; i < Vn / 4; i += 256) dst[i] = src[i];
  __syncthreads();

  // pass 1: row max + gumbel argmax (first-index tiebreak)
  float m = -INFINITY, best = -INFINITY;
  int bidx = Vn;
  for (int v = tid; v < Vn; v += 256) {
    float lg = row[v];
    m = fmaxf(m, lg);
    unsigned j = (unsigned)(b * Vn + v);
    unsigned y0, y1;
    threefry2x32(k0, k1, 0u, j, y0, y1);
    unsigned bits = y0 ^ y1;
    float uf = fmaxf(__uint_as_float((bits >> 9) | 0x3F800000u) - 1.0f,
                     1.17549435e-38f);
    float g = -__logf(-__logf(uf));
    float val = lg + g;
    if (val > best) { best = val; bidx = v; }   // ascending v -> first max kept
  }
  rf[tid] = m;
  __syncthreads();
  for (int s = 128; s > 0; s >>= 1) {
    if (tid < s) rf[tid] = fmaxf(rf[tid], rf[tid + s]);
    __syncthreads();
  }
  float rowmax = rf[0];
  __syncthreads();
  rf[tid] = best; ri[tid] = bidx;
  __syncthreads();
  for (int s = 128; s > 0; s >>= 1) {
    if (tid < s) {
      float v2 = rf[tid + s]; int i2 = ri[tid + s];
      if (v2 > rf[tid] || (v2 == rf[tid] && i2 < ri[tid])) { rf[tid] = v2; ri[tid] = i2; }
    }
    __syncthreads();
  }
  int act = ri[0];

  // pass 2: S = sum e^sh, T = sum e^sh * sh (f64 adds)
  double sacc = 0.0, tacc = 0.0;
  for (int v = tid; v < Vn; v += 256) {
    float sh = row[v] - rowmax;
    float e = __expf(sh);
    sacc += (double)e;
    tacc += (double)(e * sh);
  }
  rd[tid] = sacc; rt[tid] = tacc;
  __syncthreads();
  for (int s = 128; s > 0; s >>= 1) {
    if (tid < s) { rd[tid] += rd[tid + s]; rt[tid] += rt[tid + s]; }
    __syncthreads();
  }
  double S = rd[0], T = rt[0];
  double lse = log(S);
  float mk = mask[b];

  // pass 3 (float4): probs + lps
  float* probs = out_base + 3 * Bn * Tn + ((size_t)(b * Tn + t)) * Vn;
  for (int v0 = tid << 2; v0 < Vn; v0 += 1024) {
    float4 l4 = *(const float4*)&row[v0];
    float lp[4];
    lp[0] = (float)((double)(l4.x - rowmax) - lse);
    lp[1] = (float)((double)(l4.y - rowmax) - lse);
    lp[2] = (float)((double)(l4.z - rowmax) - lse);
    lp[3] = (float)((double)(l4.w - rowmax) - lse);
    float4 o = {__expf(lp[0]) * mk, __expf(lp[1]) * mk,
                __expf(lp[2]) * mk, __expf(lp[3]) * mk};
    *(float4*)&probs[v0] = o;
    int d = act - v0;
    if (d >= 0 && d < 4)
      out_base[Bn * Tn + b * Tn + t] = lp[d] * mk;  // lps
  }
  // fused next-input: x = emb[act] (split), mask update (eos=0)
  for (int j = tid; j < Hn; j += 256) {
    float v = emb[(size_t)act * Hn + j];
    split16(v, xh[(size_t)b * Hn + j], xl[(size_t)b * Hn + j]);
  }
  if (tid == 0) {
    out_base[2 * Bn * Tn + b * Tn + t] = (float)(lse - T / S) * mk;  // ents
    out_base[b * Tn + t] = (float)act;                               // msgs
    mask[b] = mk * (act == 0 ? 0.f : 1.f);
  }
}

extern "C" void kernel_launch(void* const* d_in, const int* in_sizes, int n_in,
                              void* d_out, int out_size, void* d_ws, size_t ws_size,
                              hipStream_t stream) {
  const float* img  = (const float*)d_in[0];
  const float* emb  = (const float*)d_in[1];
  const float* fc1w = (const float*)d_in[2];
  const float* fc1b = (const float*)d_in[3];
  const float* wih  = (const float*)d_in[4];
  const float* whh  = (const float*)d_in[5];
  const float* bih  = (const float*)d_in[6];
  const float* bhh  = (const float*)d_in[7];
  const float* outw = (const float*)d_in[8];
  const float* outb = (const float*)d_in[9];
  float* out = (float*)d_out;

  float* ws = (float*)d_ws;
  float* c      = ws;                          // B*H
  float* mask   = c + Bn * Hn;                 // B
  float* biasp  = mask + Bn;                   // G4
  float* logits = biasp + G4;                  // B*V
  _Float16* wph  = (_Float16*)(logits + (size_t)Bn * Vn);  // permuted wih hi
  _Float16* wpl  = wph + (size_t)G4 * Hn;
  _Float16* vph  = wpl + (size_t)G4 * Hn;                  // permuted whh hi
  _Float16* vpl  = vph + (size_t)G4 * Hn;
  _Float16* outwh = vpl + (size_t)G4 * Hn;
  _Float16* outwl = outwh + (size_t)Vn * Hn;
  _Float16* xh = outwl + (size_t)Vn * Hn;
  _Float16* xl = xh + Bn * Hn;
  _Float16* hhA = xl + Bn * Hn;
  _Float16* hlA = hhA + Bn * Hn;
  _Float16* hhB = hlA + Bn * Hn;
  _Float16* hlB = hhB + Bn * Hn;

  // step keys: fold-like split (jax_threefry_partitionable):
  // keys[t] = threefry2x32(key=(0,42), x0=0, x1=t)
  unsigned kk0[Tn], kk1[Tn];
  for (int i = 0; i < Tn; ++i) {
    unsigned y0, y1;
    threefry2x32(0u, 42u, 0u, (unsigned)i, y0, y1);
    kk0[i] = y0; kk1[i] = y1;
  }

  // dynamic-LDS opt-in (>64KB). Non-stream calls; graph-capture safe. If the
  // stack rejects them, fall back to the proven static-LDS kernels.
  bool big_lds =
      (hipFuncSetAttribute((const void*)k_gates,
                           hipFuncAttributeMaxDynamicSharedMemorySize, 147456) == hipSuccess) &&
      (hipFuncSetAttribute((const void*)k_logits,
                           hipFuncAttributeMaxDynamicSharedMemorySize, 147456) == hipSuccess);

  // one-time preps
  k_prep_perm<<<(G4 * Hn) / 256, 256, 0, stream>>>(wih, wph, wpl);
  k_prep_perm<<<(G4 * Hn) / 256, 256, 0, stream>>>(whh, vph, vpl);
  k_prep<<<(Vn * Hn) / 256, 256, 0, stream>>>(outw, outwh, outwl, Vn * Hn);
  k_prep_bias<<<G4 / 256, 256, 0, stream>>>(bih, bhh, biasp);
  k_mask<<<4, 256, 0, stream>>>(mask);
  k_fc1<<<64, 256, 0, stream>>>(img, fc1w, fc1b, hhA, hlA, xh, xl, c);

  for (int t = 0; t < Tn; ++t) {
    const _Float16* hih = (t & 1) ? hhB : hhA;
    const _Float16* hil = (t & 1) ? hlB : hlA;
    _Float16* hoh = (t & 1) ? hhA : hhB;
    _Float16* hol = (t & 1) ? hlA : hlB;
    if (big_lds) {
      k_gates<<<256, 512, 147456, stream>>>(
          xh, xl, hih, hil, wph, wpl, vph, vpl, biasp, c, hoh, hol);
      k_logits<<<256, 512, 147456, stream>>>(
          hoh, hol, outwh, outwl, outb, logits);
    } else {
      k_gates_fb<<<256, 256, 0, stream>>>(
          xh, xl, hih, hil, wph, wpl, vph, vpl, biasp, c, hoh, hol);
      k_logits_fb<<<512, 256, 0, stream>>>(
          hoh, hol, outwh, outwl, outb, logits);
    }
    k_sm<<<Bn, 256, 0, stream>>>(logits, emb, mask, out, xh, xl, kk0[t], kk1[t], t);
  }
}

// Round 17
// 1814.510 us; speedup vs baseline: 1.1217x; 1.0467x over previous
//
#include <hip/hip_runtime.h>
#include <math.h>

#define Bn 1024
#define Dn 512
#define Hn 512
#define Vn 8192
#define Tn 20
#define G4 2048

typedef _Float16 half8 __attribute__((ext_vector_type(8)));
typedef float f32x4 __attribute__((ext_vector_type(4)));

#define SCHEDB() __builtin_amdgcn_sched_barrier(0)
#define SBAR()   __builtin_amdgcn_s_barrier()

// ---------------- threefry2x32 (JAX-exact, 20 rounds) ----------------
__host__ __device__ __forceinline__ void threefry2x32(
    unsigned k0, unsigned k1, unsigned x0, unsigned x1,
    unsigned& y0, unsigned& y1) {
  unsigned ks2 = k0 ^ k1 ^ 0x1BD11BDAu;
#define TF_RND(r) { x0 += x1; x1 = (x1 << (r)) | (x1 >> (32 - (r))); x1 ^= x0; }
  x0 += k0; x1 += k1;
  TF_RND(13) TF_RND(15) TF_RND(26) TF_RND(6)
  x0 += k1; x1 += ks2 + 1u;
  TF_RND(17) TF_RND(29) TF_RND(16) TF_RND(24)
  x0 += ks2; x1 += k0 + 2u;
  TF_RND(13) TF_RND(15) TF_RND(26) TF_RND(6)
  x0 += k0; x1 += k1 + 3u;
  TF_RND(17) TF_RND(29) TF_RND(16) TF_RND(24)
  x0 += k1; x1 += ks2 + 4u;
  TF_RND(13) TF_RND(15) TF_RND(26) TF_RND(6)
  x0 += ks2; x1 += k0 + 5u;
#undef TF_RND
  y0 = x0; y1 = x1;
}

// f32 -> f16 hi/lo split. lo scaled by 2^11 to stay in f16 normal range.
__device__ __forceinline__ void split16(float v, _Float16& hi, _Float16& lo) {
  float h = (fabsf(v) < 6.2e-5f) ? 0.f : (float)(_Float16)v;  // keep hi out of f16-denorm
  hi = (_Float16)h;
  lo = (_Float16)((v - h) * 2048.0f);
}

// async 16B global->LDS. HW dest = wave-uniform base + lane*16; our per-lane
// addressing (row=f(lane>>2), chunk=lane&3) equals exactly that mapping.
__device__ __forceinline__ void gload16(void* l, const void* g) {
  __builtin_amdgcn_global_load_lds(
      (const __attribute__((address_space(1))) unsigned int*)g,
      (__attribute__((address_space(3))) unsigned int*)l, 16, 0, 0);
}

// ---------------- prep kernels (run every call; idempotent) ----------------
__global__ void k_prep(const float* __restrict__ w, _Float16* __restrict__ hi,
                       _Float16* __restrict__ lo, int n) {
  int i = blockIdx.x * blockDim.x + threadIdx.x;
  if (i >= n) return;
  split16(w[i], hi[i], lo[i]);
}

// gate-interleaved permutation: dst row u*4+g  <-  src row g*512+u
__global__ void k_prep_perm(const float* __restrict__ w, _Float16* __restrict__ hi,
                            _Float16* __restrict__ lo) {
  int i = blockIdx.x * blockDim.x + threadIdx.x;  // G4*Hn
  int rp = i >> 9, k = i & 511;
  int u = rp >> 2, g = rp & 3;
  split16(w[(size_t)((g << 9) + u) * 512 + k], hi[i], lo[i]);
}

__global__ void k_prep_bias(const float* __restrict__ bih, const float* __restrict__ bhh,
                            float* __restrict__ bp) {
  int i = blockIdx.x * blockDim.x + threadIdx.x;  // G4
  if (i >= G4) return;
  int u = i >> 2, g = i & 3;
  bp[i] = bih[(g << 9) + u] + bhh[(g << 9) + u];
}

__global__ void k_mask(float* __restrict__ mask) {
  int i = blockIdx.x * blockDim.x + threadIdx.x;
  if (i < Bn) mask[i] = 1.f;
}

// ================== gates GEMM: 8-wave 128x64, BK=64, 3-buf counted vmcnt(6) ==========
__global__ void __launch_bounds__(512) k_gates(
    const _Float16* __restrict__ xh, const _Float16* __restrict__ xl,
    const _Float16* __restrict__ hih, const _Float16* __restrict__ hil,
    const _Float16* __restrict__ wph, const _Float16* __restrict__ wpl,
    const _Float16* __restrict__ vph, const _Float16* __restrict__ vpl,
    const float* __restrict__ biasp, float* __restrict__ c,
    _Float16* __restrict__ hoh, _Float16* __restrict__ hol) {
  extern __shared__ __align__(16) char smem[];
  int tid = threadIdx.x;
  f32x4 acch[4] = {};
  f32x4 accc[4] = {};
  int x8 = blockIdx.x & 7, q = blockIdx.x >> 3;          // grid 256
  int bn = (((q & 3) << 3) | x8) << 6;
  int bm = (q >> 2) << 7;
  int lane = tid & 63, wv = tid >> 6;                    // 8 waves
  int wr = (wv >> 2) << 6, wc = (wv & 3) << 4;           // 2M x 4N
  int fr = lane & 15, c0 = lane >> 4;
  int rsub = lane >> 2, cp = lane & 3;
  int psw = (c0 ^ ((fr >> 1) & 3)) << 3;

  auto stage_sub = [&](char* half_base, int kk) {
    const _Float16* As_h = (kk < 16) ? xh : hih;
    const _Float16* As_l = (kk < 16) ? xl : hil;
    const _Float16* Bs_h = (kk < 16) ? wph : vph;
    const _Float16* Bs_l = (kk < 16) ? wpl : vpl;
    int k0 = (kk & 15) << 5;
    {
      int row = (wv << 4) + rsub;                        // 0..127
      int koff = (cp ^ ((row >> 1) & 3)) << 3;
      size_t ga = (size_t)(bm + row) * 512 + k0 + koff;
      int lo = (row << 5) + (cp << 3);
      gload16((_Float16*)half_base + lo, As_h + ga);
      gload16((_Float16*)(half_base + 8192) + lo, As_l + ga);
    }
    {
      int brow = ((wv & 3) << 4) + rsub;                 // 0..63
      int bkoff = (cp ^ ((brow >> 1) & 3)) << 3;
      size_t gb = (size_t)(bn + brow) * 512 + k0 + bkoff;
      int blo = (brow << 5) + (cp << 3);
      if (wv < 4) gload16((_Float16*)(half_base + 16384) + blo, Bs_h + gb);
      else        gload16((_Float16*)(half_base + 20480) + blo, Bs_l + gb);
    }
  };
  auto stage = [&](int p, int t) {                       // t = 0..15, covers kk=2t,2t+1
    char* base = smem + p * 49152;
    stage_sub(base, 2 * t);
    stage_sub(base + 24576, 2 * t + 1);
  };
  auto compute_sub = [&](char* half_base) {
    _Float16 (*Ah)[32] = (_Float16(*)[32])half_base;
    _Float16 (*Al)[32] = (_Float16(*)[32])(half_base + 8192);
    _Float16 (*Bh)[32] = (_Float16(*)[32])(half_base + 16384);
    _Float16 (*Bl)[32] = (_Float16(*)[32])(half_base + 20480);
    half8 ah[4], al[4];
#pragma unroll
    for (int i = 0; i < 4; ++i) {
      int ra = wr + i * 16 + fr;
      ah[i] = *(const half8*)&Ah[ra][psw];
      al[i] = *(const half8*)&Al[ra][psw];
    }
    half8 bh = *(const half8*)&Bh[wc + fr][psw];
    half8 bl = *(const half8*)&Bl[wc + fr][psw];
#pragma unroll
    for (int mi = 0; mi < 4; ++mi) {
      acch[mi] = __builtin_amdgcn_mfma_f32_16x16x32_f16(ah[mi], bh, acch[mi], 0, 0, 0);
      accc[mi] = __builtin_amdgcn_mfma_f32_16x16x32_f16(ah[mi], bl, accc[mi], 0, 0, 0);
      accc[mi] = __builtin_amdgcn_mfma_f32_16x16x32_f16(al[mi], bh, accc[mi], 0, 0, 0);
    }
  };
  auto compute = [&](int p) {
    char* base = smem + p * 49152;
    compute_sub(base);
    compute_sub(base + 24576);
  };

  stage(0, 0); stage(1, 1);
  asm volatile("s_waitcnt vmcnt(6)" ::: "memory");       // drain buf0's 6, keep buf1's 6
  SCHEDB(); SBAR(); SCHEDB();
  int pc = 0, ps = 2;
  for (int t = 0; t < 16; ++t) {
    if (t + 2 < 16) stage(ps, t + 2);
    compute(pc);
    SCHEDB();
    if (t + 2 < 16) { asm volatile("s_waitcnt vmcnt(6) lgkmcnt(0)" ::: "memory"); }
    else            { asm volatile("s_waitcnt vmcnt(0) lgkmcnt(0)" ::: "memory"); }
    SCHEDB(); SBAR(); SCHEDB();
    pc = (pc == 2) ? 0 : pc + 1;
    ps = (ps == 2) ? 0 : ps + 1;
  }

  float (*gtile)[68] = (float(*)[68])smem;
  int orow = (lane >> 4) << 2, ocol = lane & 15;
  {
    int col = wc + ocol;
    float bsum = biasp[bn + col];
#pragma unroll
    for (int mi = 0; mi < 4; ++mi)
#pragma unroll
      for (int r = 0; r < 4; ++r) {
        int row = wr + mi * 16 + orow + r;
        gtile[row][col] = acch[mi][r] + accc[mi][r] * (1.0f / 2048.0f) + bsum;
      }
  }
  __syncthreads();
  // fused cell update, 512 threads: 2048 gate-quads, 4 per thread
  int u0 = bn >> 2;
#pragma unroll
  for (int j = 0; j < 4; ++j) {
    int idx = tid + (j << 9);
    int row = idx >> 4, ul = idx & 15;
    float4 gt = *(const float4*)&gtile[row][ul << 2];  // i,f,g,o
    size_t cidx = (size_t)(bm + row) * Hn + u0 + ul;
    float si = 1.0f / (1.0f + expf(-gt.x));
    float sf = 1.0f / (1.0f + expf(-gt.y));
    float tg = tanhf(gt.z);
    float so = 1.0f / (1.0f + expf(-gt.w));
    float cn = sf * c[cidx] + si * tg;
    c[cidx] = cn;
    float hv = so * tanhf(cn);
    split16(hv, hoh[cidx], hol[cidx]);
  }
}

// ================== logits GEMM: 256x128 tile, 512 thr, 3-buf counted ==================
__global__ void __launch_bounds__(512) k_logits(
    const _Float16* __restrict__ hh, const _Float16* __restrict__ hl,
    const _Float16* __restrict__ outwh, const _Float16* __restrict__ outwl,
    const float* __restrict__ outb, float* __restrict__ logits) {
  extern __shared__ __align__(16) char smem[];
  int tid = threadIdx.x;
  f32x4 acch[4][4] = {};
  f32x4 accc[4][4] = {};
  int x8 = blockIdx.x & 7, q = blockIdx.x >> 3;          // grid 256
  int bn = (((q & 7) << 3) | x8) << 7;                   // 64 n-blocks of 128
  int bm = (q >> 3) << 8;                                // 4 m-blocks of 256
  int lane = tid & 63, wv = tid >> 6;                    // 8 waves
  int wr = (wv >> 1) << 6, wc = (wv & 1) << 6;
  int fr = lane & 15, c0 = lane >> 4;
  int rsub = lane >> 2, cp = lane & 3;
  int psw = (c0 ^ ((fr >> 1) & 3)) << 3;

  auto stage = [&](int p, int t) {
    int k0 = t << 5;
    char* base = smem + p * 49152;
#pragma unroll
    for (int s = 0; s < 2; ++s) {
      int row = (((wv << 1) + s) << 4) + rsub;           // 0..255
      int koff = (cp ^ ((row >> 1) & 3)) << 3;
      size_t ga = (size_t)(bm + row) * 512 + k0 + koff;
      int lo = (row << 5) + (cp << 3);
      gload16((_Float16*)base + lo, hh + ga);
      gload16((_Float16*)(base + 16384) + lo, hl + ga);
    }
    {
      int row = tid >> 2;                                 // 0..127
      int koff = (cp ^ ((row >> 1) & 3)) << 3;
      size_t gb = (size_t)(bn + row) * 512 + k0 + koff;
      int lo = (row << 5) + (cp << 3);
      gload16((_Float16*)(base + 32768) + lo, outwh + gb);
      gload16((_Float16*)(base + 40960) + lo, outwl + gb);
    }
  };
  auto compute = [&](int p) {
    char* base = smem + p * 49152;
    _Float16 (*Ah)[32] = (_Float16(*)[32])base;
    _Float16 (*Al)[32] = (_Float16(*)[32])(base + 16384);
    _Float16 (*Bh)[32] = (_Float16(*)[32])(base + 32768);
    _Float16 (*Bl)[32] = (_Float16(*)[32])(base + 40960);
    half8 ah[4], al[4], bh[4], bl[4];
#pragma unroll
    for (int i = 0; i < 4; ++i) {
      int ra = wr + i * 16 + fr;
      int rb = wc + i * 16 + fr;
      ah[i] = *(const half8*)&Ah[ra][psw];
      al[i] = *(const half8*)&Al[ra][psw];
      bh[i] = *(const half8*)&Bh[rb][psw];
      bl[i] = *(const half8*)&Bl[rb][psw];
    }
#pragma unroll
    for (int mi = 0; mi < 4; ++mi)
#pragma unroll
      for (int ni = 0; ni < 4; ++ni) {
        acch[mi][ni] = __builtin_amdgcn_mfma_f32_16x16x32_f16(ah[mi], bh[ni], acch[mi][ni], 0, 0, 0);
        accc[mi][ni] = __builtin_amdgcn_mfma_f32_16x16x32_f16(ah[mi], bl[ni], accc[mi][ni], 0, 0, 0);
        accc[mi][ni] = __builtin_amdgcn_mfma_f32_16x16x32_f16(al[mi], bh[ni], accc[mi][ni], 0, 0, 0);
      }
  };

  stage(0, 0); stage(1, 1);
  asm volatile("s_waitcnt vmcnt(6)" ::: "memory");
  SCHEDB(); SBAR(); SCHEDB();
  int pc = 0, ps = 2;
  for (int t = 0; t < 16; ++t) {
    if (t + 2 < 16) stage(ps, t + 2);
    compute(pc);
    SCHEDB();
    if (t + 2 < 16) { asm volatile("s_waitcnt vmcnt(6) lgkmcnt(0)" ::: "memory"); }
    else            { asm volatile("s_waitcnt vmcnt(0) lgkmcnt(0)" ::: "memory"); }
    SCHEDB(); SBAR(); SCHEDB();
    pc = (pc == 2) ? 0 : pc + 1;
    ps = (ps == 2) ? 0 : ps + 1;
  }

  int orow = (lane >> 4) << 2, ocol = lane & 15;
#pragma unroll
  for (int mi = 0; mi < 4; ++mi)
#pragma unroll
    for (int ni = 0; ni < 4; ++ni) {
      int colg = bn + wc + ni * 16 + ocol;
      float bv = outb[colg];
#pragma unroll
      for (int r = 0; r < 4; ++r) {
        int rowg = bm + wr + mi * 16 + orow + r;
        logits[(size_t)rowg * Vn + colg] =
            acch[mi][ni][r] + accc[mi][ni][r] * (1.0f / 2048.0f) + bv;
      }
    }
}

// ================== FALLBACK kernels (R8-proven, static <=64KB LDS) ==================
__device__ __forceinline__ void cell_update256(
    float (*gtile)[68], int tid, int bm, int u0, float* __restrict__ c,
    _Float16* __restrict__ hoh, _Float16* __restrict__ hol) {
#pragma unroll
  for (int j = 0; j < 8; ++j) {
    int idx = tid + (j << 8);
    int row = idx >> 4, ul = idx & 15;
    float4 gt = *(const float4*)&gtile[row][ul << 2];
    size_t cidx = (size_t)(bm + row) * Hn + u0 + ul;
    float si = 1.0f / (1.0f + expf(-gt.x));
    float sf = 1.0f / (1.0f + expf(-gt.y));
    float tg = tanhf(gt.z);
    float so = 1.0f / (1.0f + expf(-gt.w));
    float cn = sf * c[cidx] + si * tg;
    c[cidx] = cn;
    float hv = so * tanhf(cn);
    split16(hv, hoh[cidx], hol[cidx]);
  }
}

__global__ void __launch_bounds__(256) k_gates_fb(
    const _Float16* __restrict__ xh, const _Float16* __restrict__ xl,
    const _Float16* __restrict__ hih, const _Float16* __restrict__ hil,
    const _Float16* __restrict__ wph, const _Float16* __restrict__ wpl,
    const _Float16* __restrict__ vph, const _Float16* __restrict__ vpl,
    const float* __restrict__ biasp, float* __restrict__ c,
    _Float16* __restrict__ hoh, _Float16* __restrict__ hol) {
  __shared__ __align__(16) char smem[49152];
  int tid = threadIdx.x;
  f32x4 acch[4][2] = {};
  f32x4 accc[4][2] = {};
  int x8 = blockIdx.x & 7, q = blockIdx.x >> 3;
  int bn = (((q & 3) << 3) | x8) << 6;
  int bm = (q >> 2) << 7;
  int lane = tid & 63, wv = tid >> 6;
  int wr = (wv >> 1) << 6, wc = (wv & 1) << 5;
  int fr = lane & 15, c0 = lane >> 4;
  int rsub = lane >> 2, cp = lane & 3;
  int psw = (c0 ^ ((fr >> 1) & 3)) << 3;
  auto stage = [&](int p, int t) {
    const _Float16* As_h = (t < 16) ? xh : hih;
    const _Float16* As_l = (t < 16) ? xl : hil;
    const _Float16* Bs_h = (t < 16) ? wph : vph;
    const _Float16* Bs_l = (t < 16) ? wpl : vpl;
    int k0 = (t & 15) << 5;
    char* base = smem + p * 24576;
#pragma unroll
    for (int s = 0; s < 2; ++s) {
      int row = (((wv << 1) + s) << 4) + rsub;
      int koff = (cp ^ ((row >> 1) & 3)) << 3;
      size_t ga = (size_t)(bm + row) * 512 + k0 + koff;
      int lo = (row << 5) + (cp << 3);
      gload16((_Float16*)base + lo, As_h + ga);
      gload16((_Float16*)(base + 8192) + lo, As_l + ga);
    }
    {
      int row = (wv << 4) + rsub;
      int koff = (cp ^ ((row >> 1) & 3)) << 3;
      size_t gb = (size_t)(bn + row) * 512 + k0 + koff;
      int lo = (row << 5) + (cp << 3);
      gload16((_Float16*)(base + 16384) + lo, Bs_h + gb);
      gload16((_Float16*)(base + 20480) + lo, Bs_l + gb);
    }
  };
  auto compute = [&](int p) {
    char* base = smem + p * 24576;
    _Float16 (*Ah)[32] = (_Float16(*)[32])base;
    _Float16 (*Al)[32] = (_Float16(*)[32])(base + 8192);
    _Float16 (*Bh)[32] = (_Float16(*)[32])(base + 16384);
    _Float16 (*Bl)[32] = (_Float16(*)[32])(base + 20480);
    half8 ah[4], al[4], bh[2], bl[2];
#pragma unroll
    for (int i = 0; i < 4; ++i) {
      int ra = wr + i * 16 + fr;
      ah[i] = *(const half8*)&Ah[ra][psw];
      al[i] = *(const half8*)&Al[ra][psw];
    }
#pragma unroll
    for (int i = 0; i < 2; ++i) {
      int rb = wc + i * 16 + fr;
      bh[i] = *(const half8*)&Bh[rb][psw];
      bl[i] = *(const half8*)&Bl[rb][psw];
    }
#pragma unroll
    for (int mi = 0; mi < 4; ++mi)
#pragma unroll
      for (int ni = 0; ni < 2; ++ni) {
        acch[mi][ni] = __builtin_amdgcn_mfma_f32_16x16x32_f16(ah[mi], bh[ni], acch[mi][ni], 0, 0, 0);
        accc[mi][ni] = __builtin_amdgcn_mfma_f32_16x16x32_f16(ah[mi], bl[ni], accc[mi][ni], 0, 0, 0);
        accc[mi][ni] = __builtin_amdgcn_mfma_f32_16x16x32_f16(al[mi], bh[ni], accc[mi][ni], 0, 0, 0);
      }
  };
  stage(0, 0); stage(1, 1);
  asm volatile("s_waitcnt vmcnt(6)" ::: "memory");
  SCHEDB(); SBAR(); SCHEDB();
  int pc = 0, ps = 2;
  for (int t = 0; t < 32; ++t) {
    if (t + 2 < 32) stage(ps, t + 2);
    compute(pc);
    SCHEDB();
    if (t + 2 < 32) { asm volatile("s_waitcnt vmcnt(6) lgkmcnt(0)" ::: "memory"); }
    else            { asm volatile("s_waitcnt vmcnt(0) lgkmcnt(0)" ::: "memory"); }
    SCHEDB(); SBAR(); SCHEDB();
    pc = (pc == 2) ? 0 : pc + 1;
    ps = (ps == 2) ? 0 : ps + 1;
  }
  float (*gtile)[68] = (float(*)[68])smem;
  int orow = (lane >> 4) << 2, ocol = lane & 15;
#pragma unroll
  for (int mi = 0; mi < 4; ++mi)
#pragma unroll
    for (int ni = 0; ni < 2; ++ni) {
      int col = wc + ni * 16 + ocol;
      float bsum = biasp[bn + col];
#pragma unroll
      for (int r = 0; r < 4; ++r) {
        int row = wr + mi * 16 + orow + r;
        gtile[row][col] = acch[mi][ni][r] + accc[mi][ni][r] * (1.0f / 2048.0f) + bsum;
      }
    }
  __syncthreads();
  cell_update256(gtile, tid, bm, bn >> 2, c, hoh, hol);
}

__global__ void __launch_bounds__(256) k_logits_fb(
    const _Float16* __restrict__ hh, const _Float16* __restrict__ hl,
    const _Float16* __restrict__ outwh, const _Float16* __restrict__ outwl,
    const float* __restrict__ outb, float* __restrict__ logits) {
  __shared__ __align__(16) char smem[65536];
  int tid = threadIdx.x;
  f32x4 acch[4][4] = {};
  f32x4 accc[4][4] = {};
  int x8 = blockIdx.x & 7, q = blockIdx.x >> 3;          // grid 512
  int bn = (((q & 7) << 3) | x8) << 7;
  int bm = (q >> 3) << 7;
  int lane = tid & 63, wv = tid >> 6;
  int wr = (wv >> 1) << 6, wc = (wv & 1) << 6;
  int fr = lane & 15, c0 = lane >> 4;
  int rsub = lane >> 2, cp = lane & 3;
  int psw = (c0 ^ ((fr >> 1) & 3)) << 3;
  auto stage = [&](int p, int t) {
    int k0 = t << 5;
    char* base = smem + (p << 15);
#pragma unroll
    for (int s = 0; s < 2; ++s) {
      int row = (((wv << 1) + s) << 4) + rsub;
      int koff = (cp ^ ((row >> 1) & 3)) << 3;
      size_t ga = (size_t)(bm + row) * 512 + k0 + koff;
      size_t gb = (size_t)(bn + row) * 512 + k0 + koff;
      int lo = (row << 5) + (cp << 3);
      gload16((_Float16*)base + lo, hh + ga);
      gload16((_Float16*)(base + 8192) + lo, hl + ga);
      gload16((_Float16*)(base + 16384) + lo, outwh + gb);
      gload16((_Float16*)(base + 24576) + lo, outwl + gb);
    }
  };
  auto compute = [&](int p) {
    char* base = smem + (p << 15);
    _Float16 (*Ah)[32] = (_Float16(*)[32])base;
    _Float16 (*Al)[32] = (_Float16(*)[32])(base + 8192);
    _Float16 (*Bh)[32] = (_Float16(*)[32])(base + 16384);
    _Float16 (*Bl)[32] = (_Float16(*)[32])(base + 24576);
    half8 ah[4], al[4], bh[4], bl[4];
#pragma unroll
    for (int i = 0; i < 4; ++i) {
      int ra = wr + i * 16 + fr;
      int rb = wc + i * 16 + fr;
      ah[i] = *(const half8*)&Ah[ra][psw];
      al[i] = *(const half8*)&Al[ra][psw];
      bh[i] = *(const half8*)&Bh[rb][psw];
      bl[i] = *(const half8*)&Bl[rb][psw];
    }
#pragma unroll
    for (int mi = 0; mi < 4; ++mi)
#pragma unroll
      for (int ni = 0; ni < 4; ++ni) {
        acch[mi][ni] = __builtin_amdgcn_mfma_f32_16x16x32_f16(ah[mi], bh[ni], acch[mi][ni], 0, 0, 0);
        accc[mi][ni] = __builtin_amdgcn_mfma_f32_16x16x32_f16(ah[mi], bl[ni], accc[mi][ni], 0, 0, 0);
        accc[mi][ni] = __builtin_amdgcn_mfma_f32_16x16x32_f16(al[mi], bh[ni], accc[mi][ni], 0, 0, 0);
      }
  };
  stage(0, 0);
  __syncthreads();
  int cur = 0;
  for (int t = 0; t < 16; ++t) {
    if (t + 1 < 16) stage(cur ^ 1, t + 1);
    compute(cur);
    __syncthreads();
    cur ^= 1;
  }
  int orow = (lane >> 4) << 2, ocol = lane & 15;
#pragma unroll
  for (int mi = 0; mi < 4; ++mi)
#pragma unroll
    for (int ni = 0; ni < 4; ++ni) {
      int colg = bn + wc + ni * 16 + ocol;
      float bv = outb[colg];
#pragma unroll
      for (int r = 0; r < 4; ++r) {
        int rowg = bm + wr + mi * 16 + orow + r;
        logits[(size_t)rowg * Vn + colg] =
            acch[mi][ni][r] + accc[mi][ni][r] * (1.0f / 2048.0f) + bv;
      }
    }
}

// ---------------- f32 register-tiled GEMM (k_fc1 only, runs once) ----------
__device__ __forceinline__ void gemm_seg(
    const float* __restrict__ A, int lda, const float* __restrict__ W, int ldw,
    int bm, int bn, int tid, int tm8, int tn4,
    float (*As)[132], float (*Bs)[68], float acc[8][4]) {
  for (int k0 = 0; k0 < 512; k0 += 16) {
#pragma unroll
    for (int it = 0; it < 2; ++it) {
      int g = (it << 8) + tid;
      int m = g >> 2, kq = g & 3;
      const float4 v = *(const float4*)(A + (size_t)(bm + m) * lda + k0 + (kq << 2));
      As[(kq << 2) + 0][m] = v.x; As[(kq << 2) + 1][m] = v.y;
      As[(kq << 2) + 2][m] = v.z; As[(kq << 2) + 3][m] = v.w;
    }
    {
      int m = tid >> 2, kq = tid & 3;
      const float4 v = *(const float4*)(W + (size_t)(bn + m) * ldw + k0 + (kq << 2));
      Bs[(kq << 2) + 0][m] = v.x; Bs[(kq << 2) + 1][m] = v.y;
      Bs[(kq << 2) + 2][m] = v.z; Bs[(kq << 2) + 3][m] = v.w;
    }
    __syncthreads();
#pragma unroll
    for (int k = 0; k < 16; ++k) {
      const float4 a0 = *(const float4*)&As[k][tm8];
      const float4 a1 = *(const float4*)&As[k][tm8 + 4];
      const float4 bv = *(const float4*)&Bs[k][tn4];
      float av[8] = {a0.x, a0.y, a0.z, a0.w, a1.x, a1.y, a1.z, a1.w};
      float bw[4] = {bv.x, bv.y, bv.z, bv.w};
#pragma unroll
      for (int i = 0; i < 8; ++i)
#pragma unroll
        for (int j = 0; j < 4; ++j)
          acc[i][j] = fmaf(av[i], bw[j], acc[i][j]);
    }
    __syncthreads();
  }
}

// ---------------- init: h0 = relu(img@fc1^T + b) -> hh/hl; c=0; x=0 --------
__global__ void __launch_bounds__(256) k_fc1(
    const float* __restrict__ img, const float* __restrict__ fc1w,
    const float* __restrict__ fc1b,
    _Float16* __restrict__ hh, _Float16* __restrict__ hl,
    _Float16* __restrict__ xh, _Float16* __restrict__ xl,
    float* __restrict__ c) {
  __shared__ float As[16][132];
  __shared__ float Bs[16][68];
  int tid = threadIdx.x;
  int tm8 = (tid >> 4) << 3;
  int tn4 = (tid & 15) << 2;
  float acc[8][4] = {};
  int bm = (blockIdx.x >> 3) << 7;
  int bn = (blockIdx.x & 7) << 6;
  gemm_seg(img, Dn, fc1w, Dn, bm, bn, tid, tm8, tn4, As, Bs, acc);
  const float4 b4 = *(const float4*)(fc1b + bn + tn4);
  float bb[4] = {b4.x, b4.y, b4.z, b4.w};
#pragma unroll
  for (int i = 0; i < 8; ++i) {
    size_t off = (size_t)(bm + tm8 + i) * Hn + bn + tn4;
#pragma unroll
    for (int j = 0; j < 4; ++j) {
      float hv = fmaxf(acc[i][j] + bb[j], 0.f);
      split16(hv, hh[off + j], hl[off + j]);
      xh[off + j] = (_Float16)0.f;
      xl[off + j] = (_Float16)0.f;
      c[off + j] = 0.f;
    }
  }
}

// ---------------- fused softmax + gumbel-argmax + outputs + next-x ---------
// Partitionable threefry: bits(j) = y0 ^ y1, (y0,y1) = threefry(step_key, 0, j), j = b*V+v.
// Native __logf/__expf validated R11-R14 (identical sampling, absmax 1.9e-6).
// Entropy folded into pass 2: ent = lse - T/S. Pass 3 in f32 (error <= 1 ulp(lse)).
// probs stores are non-temporal (ext-vector f32x4, clang-compatible): written
// once, never read; keeps weight panels L2-resident across steps.
__global__ void __launch_bounds__(256) k_sm(
    const float* __restrict__ logits, const float* __restrict__ emb,
    float* __restrict__ mask, float* __restrict__ out_base,
    _Float16* __restrict__ xh, _Float16* __restrict__ xl,
    unsigned k0, unsigned k1, int t) {
  __shared__ __align__(16) float row[Vn];
  __shared__ float rf[256];
  __shared__ int ri[256];
  __shared__ double rd[256];
  __shared__ double rt[256];
  int b = blockIdx.x, tid = threadIdx.x;
  const float4* src = (const float4*)(logits + (size_t)b * Vn);
  float4* dst = (float4*)row;
  for (int i = tid; i < Vn / 4; i += 256) dst[i] = src[i];
  __syncthreads();

  // pass 1: row max + gumbel argmax (first-index tiebreak)
  float m = -INFINITY, best = -INFINITY;
  int bidx = Vn;
  for (int v = tid; v < Vn; v += 256) {
    float lg = row[v];
    m = fmaxf(m, lg);
    unsigned j = (unsigned)(b * Vn + v);
    unsigned y0, y1;
    threefry2x32(k0, k1, 0u, j, y0, y1);
    unsigned bits = y0 ^ y1;
    float uf = fmaxf(__uint_as_float((bits >> 9) | 0x3F800000u) - 1.0f,
                     1.17549435e-38f);
    float g = -__logf(-__logf(uf));
    float val = lg + g;
    if (val > best) { best = val; bidx = v; }   // ascending v -> first max kept
  }
  rf[tid] = m;
  __syncthreads();
  for (int s = 128; s > 0; s >>= 1) {
    if (tid < s) rf[tid] = fmaxf(rf[tid], rf[tid + s]);
    __syncthreads();
  }
  float rowmax = rf[0];
  __syncthreads();
  rf[tid] = best; ri[tid] = bidx;
  __syncthreads();
  for (int s = 128; s > 0; s >>= 1) {
    if (tid < s) {
      float v2 = rf[tid + s]; int i2 = ri[tid + s];
      if (v2 > rf[tid] || (v2 == rf[tid] && i2 < ri[tid])) { rf[tid] = v2; ri[tid] = i2; }
    }
    __syncthreads();
  }
  int act = ri[0];

  // pass 2: S = sum e^sh, T = sum e^sh * sh (f64 adds)
  double sacc = 0.0, tacc = 0.0;
  for (int v = tid; v < Vn; v += 256) {
    float sh = row[v] - rowmax;
    float e = __expf(sh);
    sacc += (double)e;
    tacc += (double)(e * sh);
  }
  rd[tid] = sacc; rt[tid] = tacc;
  __syncthreads();
  for (int s = 128; s > 0; s >>= 1) {
    if (tid < s) { rd[tid] += rd[tid + s]; rt[tid] += rt[tid + s]; }
    __syncthreads();
  }
  double S = rd[0], T = rt[0];
  double lse = log(S);
  float lsef = (float)lse;
  float mk = mask[b];

  // pass 3 (f32x4): probs + lps; non-temporal probs stores
  float* probs = out_base + 3 * Bn * Tn + ((size_t)(b * Tn + t)) * Vn;
  for (int v0 = tid << 2; v0 < Vn; v0 += 1024) {
    float4 l4 = *(const float4*)&row[v0];
    float lp[4];
    lp[0] = (l4.x - rowmax) - lsef;
    lp[1] = (l4.y - rowmax) - lsef;
    lp[2] = (l4.z - rowmax) - lsef;
    lp[3] = (l4.w - rowmax) - lsef;
    f32x4 o = {__expf(lp[0]) * mk, __expf(lp[1]) * mk,
               __expf(lp[2]) * mk, __expf(lp[3]) * mk};
    __builtin_nontemporal_store(o, (f32x4*)&probs[v0]);
    int d = act - v0;
    if (d >= 0 && d < 4)
      out_base[Bn * Tn + b * Tn + t] = lp[d] * mk;  // lps
  }
  // fused next-input: x = emb[act] (split), mask update (eos=0)
  for (int j = tid; j < Hn; j += 256) {
    float v = emb[(size_t)act * Hn + j];
    split16(v, xh[(size_t)b * Hn + j], xl[(size_t)b * Hn + j]);
  }
  if (tid == 0) {
    out_base[2 * Bn * Tn + b * Tn + t] = (float)(lse - T / S) * mk;  // ents
    out_base[b * Tn + t] = (float)act;                               // msgs
    mask[b] = mk * (act == 0 ? 0.f : 1.f);
  }
}

extern "C" void kernel_launch(void* const* d_in, const int* in_sizes, int n_in,
                              void* d_out, int out_size, void* d_ws, size_t ws_size,
                              hipStream_t stream) {
  const float* img  = (const float*)d_in[0];
  const float* emb  = (const float*)d_in[1];
  const float* fc1w = (const float*)d_in[2];
  const float* fc1b = (const float*)d_in[3];
  const float* wih  = (const float*)d_in[4];
  const float* whh  = (const float*)d_in[5];
  const float* bih  = (const float*)d_in[6];
  const float* bhh  = (const float*)d_in[7];
  const float* outw = (const float*)d_in[8];
  const float* outb = (const float*)d_in[9];
  float* out = (float*)d_out;

  float* ws = (float*)d_ws;
  float* c      = ws;                          // B*H
  float* mask   = c + Bn * Hn;                 // B
  float* biasp  = mask + Bn;                   // G4
  float* logits = biasp + G4;                  // B*V
  _Float16* wph  = (_Float16*)(logits + (size_t)Bn * Vn);  // permuted wih hi
  _Float16* wpl  = wph + (size_t)G4 * Hn;
  _Float16* vph  = wpl + (size_t)G4 * Hn;                  // permuted whh hi
  _Float16* vpl  = vph + (size_t)G4 * Hn;
  _Float16* outwh = vpl + (size_t)G4 * Hn;
  _Float16* outwl = outwh + (size_t)Vn * Hn;
  _Float16* xh = outwl + (size_t)Vn * Hn;
  _Float16* xl = xh + Bn * Hn;
  _Float16* hhA = xl + Bn * Hn;
  _Float16* hlA = hhA + Bn * Hn;
  _Float16* hhB = hlA + Bn * Hn;
  _Float16* hlB = hhB + Bn * Hn;

  // step keys: fold-like split (jax_threefry_partitionable):
  // keys[t] = threefry2x32(key=(0,42), x0=0, x1=t)
  unsigned kk0[Tn], kk1[Tn];
  for (int i = 0; i < Tn; ++i) {
    unsigned y0, y1;
    threefry2x32(0u, 42u, 0u, (unsigned)i, y0, y1);
    kk0[i] = y0; kk1[i] = y1;
  }

  // dynamic-LDS opt-in (>64KB). Non-stream calls; graph-capture safe. If the
  // stack rejects them, fall back to the proven static-LDS kernels.
  bool big_lds =
      (hipFuncSetAttribute((const void*)k_gates,
                           hipFuncAttributeMaxDynamicSharedMemorySize, 147456) == hipSuccess) &&
      (hipFuncSetAttribute((const void*)k_logits,
                           hipFuncAttributeMaxDynamicSharedMemorySize, 147456) == hipSuccess);

  // one-time preps
  k_prep_perm<<<(G4 * Hn) / 256, 256, 0, stream>>>(wih, wph, wpl);
  k_prep_perm<<<(G4 * Hn) / 256, 256, 0, stream>>>(whh, vph, vpl);
  k_prep<<<(Vn * Hn) / 256, 256, 0, stream>>>(outw, outwh, outwl, Vn * Hn);
  k_prep_bias<<<G4 / 256, 256, 0, stream>>>(bih, bhh, biasp);
  k_mask<<<4, 256, 0, stream>>>(mask);
  k_fc1<<<64, 256, 0, stream>>>(img, fc1w, fc1b, hhA, hlA, xh, xl, c);

  for (int t = 0; t < Tn; ++t) {
    const _Float16* hih = (t & 1) ? hhB : hhA;
    const _Float16* hil = (t & 1) ? hlB : hlA;
    _Float16* hoh = (t & 1) ? hhA : hhB;
    _Float16* hol = (t & 1) ? hlA : hlB;
    if (big_lds) {
      k_gates<<<256, 512, 147456, stream>>>(
          xh, xl, hih, hil, wph, wpl, vph, vpl, biasp, c, hoh, hol);
      k_logits<<<256, 512, 147456, stream>>>(
          hoh, hol, outwh, outwl, outb, logits);
    } else {
      k_gates_fb<<<256, 256, 0, stream>>>(
          xh, xl, hih, hil, wph, wpl, vph, vpl, biasp, c, hoh, hol);
      k_logits_fb<<<512, 256, 0, stream>>>(
          hoh, hol, outwh, outwl, outb, logits);
    }
    k_sm<<<Bn, 256, 0, stream>>>(logits, emb, mask, out, xh, xl, kk0[t], kk1[t], t);
  }
}